// Round 1
// baseline (4882.318 us; speedup 1.0000x reference)
//
#include <hip/hip_runtime.h>
#include <math.h>

// Problem constants
static constexpr int CB = 4;      // batch
static constexpr int CV = 2048;   // vars
static constexpr int CM = 8192;   // messages
static constexpr int CH = 64;     // hidden
static constexpr int CL = 5;      // layers
static constexpr int CT = 4;      // types
static constexpr int RR = CM * CB;        // 32768 rows (m*4+b)
// per-layer packed weight block (floats): W1cat 192x128, W2cat 128x64, b1cat 128, b2cat 64
static constexpr int WCAT_STRIDE = 192 * 128 + 128 * 64 + 128 + 64;  // 32960

// ---------------- init: feat[r*64+h] = llr[b, map[m]] * w_in[h] + b_in[h] ----------------
__global__ void k_init_feat(const float* __restrict__ llr, const int* __restrict__ map,
                            const float* __restrict__ w_in, const float* __restrict__ b_in,
                            float* __restrict__ feat) {
    int idx = blockIdx.x * blockDim.x + threadIdx.x;      // over RR*CH
    int h = idx & 63;
    int r = idx >> 6;
    int m = r >> 2;
    int b = r & 3;
    float v = llr[b * CV + map[m]];
    feat[idx] = v * w_in[h] + b_in[h];
}

// ---------------- comb: in2[r*192 + h] = feat[r*64+h] + te[type[m]][h] ----------------
__global__ void k_comb(const float* __restrict__ feat, const int* __restrict__ types,
                       const float* __restrict__ te, float* __restrict__ in2) {
    int idx = blockIdx.x * blockDim.x + threadIdx.x;      // over RR*CH
    int h = idx & 63;
    int r = idx >> 6;
    int m = r >> 2;
    int t = types[m];
    t = t < 0 ? 0 : (t > CT - 1 ? CT - 1 : t);
    in2[(size_t)r * 192 + h] = feat[idx] + te[t * CH + h];
}

// ---------------- build packed MLP weights ----------------
__global__ void k_prep(const float* __restrict__ w1v, const float* __restrict__ b1v,
                       const float* __restrict__ w2v, const float* __restrict__ b2v,
                       const float* __restrict__ w1c, const float* __restrict__ b1c,
                       const float* __restrict__ w2c, const float* __restrict__ b2c,
                       float* __restrict__ wcat) {
    int idx = blockIdx.x * blockDim.x + threadIdx.x;
    int total = CL * WCAT_STRIDE;
    if (idx >= total) return;
    int i = idx / WCAT_STRIDE;
    int e = idx % WCAT_STRIDE;
    float v;
    if (e < 24576) {                       // W1cat[j][k], 192x128
        int j = e >> 7, k = e & 127;
        if (j < 64)        v = (k < 64) ? w1v[(i * 128 + j) * 64 + k]
                                        : w1c[(i * 128 + j) * 64 + (k - 64)];
        else if (j < 128)  v = (k < 64) ? w1v[(i * 128 + j) * 64 + k] : 0.f;
        else               v = (k < 64) ? 0.f : w1c[(i * 128 + (j - 64)) * 64 + (k - 64)];
    } else if (e < 32768) {                // W2cat[k][h], 128x64
        int e2 = e - 24576; int k = e2 >> 6, h = e2 & 63;
        v = (k < 64) ? w2v[(i * 64 + k) * 64 + h]
                     : w2c[(i * 64 + (k - 64)) * 64 + h];
    } else if (e < 32896) {                // b1cat[128]
        int k = e - 32768;
        v = (k < 64) ? b1v[i * 64 + k] : b1c[i * 64 + (k - 64)];
    } else {                               // b2cat[64] = b2v + b2c
        int h = e - 32896;
        v = b2v[i * 64 + h] + b2c[i * 64 + h];
    }
    wcat[idx] = v;
}

// ---------------- generic fp32 tiled GEMM, 64x64x32, 256 thr, 4x4 microtile ----------------
// BMODE 0: B is row-major [K][ldb]. BMODE 1: B is comb slot of in2: addr n*768 + (c0/64)*192 + col
// OMODE 0: write to in2 v2c/c2v slot (slot picked by blockIdx.z); A picked by blockIdx.z
// OMODE 1: O[m*128 + c] = relu(x + bias[c])
// OMODE 2: O[m*64 + c]  = x + bias[c] (+ resid[m*64+c] if RES)
template<int BMODE, int OMODE, int RES>
__global__ __launch_bounds__(256) void k_gemm(
    const float* __restrict__ A0, const float* __restrict__ A1, int lda,
    const float* __restrict__ Bm, int ldb,
    float* __restrict__ O, const float* __restrict__ bias,
    const float* __restrict__ resid, int K) {
    __shared__ float As[32][64];
    __shared__ float Bs[32][68];   // padded: conflict-free b128 write/read

    const float* A = (OMODE == 0 && blockIdx.z) ? A1 : A0;
    const int slot = 64 + (blockIdx.z << 6);

    const int tid = threadIdx.x;
    const int m0 = blockIdx.y * 64;
    const int c0 = blockIdx.x * 64;
    const int tm = (tid & 15) * 4;
    const int tn = (tid >> 4) * 4;
    const int arow = tid & 63;
    const int akg = (tid >> 6) * 8;
    const int bk = tid >> 4;          // 0..15
    const int bc = (tid & 15) * 4;

    float acc[4][4] = {};

    for (int k0 = 0; k0 < K; k0 += 32) {
        const float* Ap = A + (size_t)(m0 + arow) * (size_t)lda + k0 + akg;
        float4 a0 = *(const float4*)Ap;
        float4 a1 = *(const float4*)(Ap + 4);
        float4 b0, b1;
        if (BMODE == 0) {
            b0 = *(const float4*)(Bm + (size_t)(k0 + bk) * (size_t)ldb + c0 + bc);
            b1 = *(const float4*)(Bm + (size_t)(k0 + bk + 16) * (size_t)ldb + c0 + bc);
        } else {
            b0 = *(const float4*)(Bm + (size_t)(k0 + bk) * 768 + (c0 >> 6) * 192 + bc);
            b1 = *(const float4*)(Bm + (size_t)(k0 + bk + 16) * 768 + (c0 >> 6) * 192 + bc);
        }
        As[akg + 0][arow] = a0.x;
        As[akg + 1][arow] = a0.y;
        As[akg + 2][arow] = a0.z;
        As[akg + 3][arow] = a0.w;
        As[akg + 4][arow] = a1.x;
        As[akg + 5][arow] = a1.y;
        As[akg + 6][arow] = a1.z;
        As[akg + 7][arow] = a1.w;
        *(float4*)&Bs[bk][bc] = b0;
        *(float4*)&Bs[bk + 16][bc] = b1;
        __syncthreads();
#pragma unroll
        for (int k = 0; k < 32; ++k) {
            float4 av = *(const float4*)&As[k][tm];
            float4 bv = *(const float4*)&Bs[k][tn];
            float a_[4] = {av.x, av.y, av.z, av.w};
            float b_[4] = {bv.x, bv.y, bv.z, bv.w};
#pragma unroll
            for (int i = 0; i < 4; ++i)
#pragma unroll
                for (int j = 0; j < 4; ++j)
                    acc[i][j] = fmaf(a_[i], b_[j], acc[i][j]);
        }
        __syncthreads();
    }

#pragma unroll
    for (int i = 0; i < 4; ++i) {
        int m = m0 + tm + i;
        float4 x = make_float4(acc[i][0], acc[i][1], acc[i][2], acc[i][3]);
        if (OMODE == 0) {
            *(float4*)&O[(size_t)m * 768 + (c0 >> 6) * 192 + slot + tn] = x;
        } else if (OMODE == 1) {
            const float4 bv = *(const float4*)&bias[c0 + tn];
            x.x = fmaxf(x.x + bv.x, 0.f);
            x.y = fmaxf(x.y + bv.y, 0.f);
            x.z = fmaxf(x.z + bv.z, 0.f);
            x.w = fmaxf(x.w + bv.w, 0.f);
            *(float4*)&O[(size_t)m * 128 + c0 + tn] = x;
        } else {
            const float4 bv = *(const float4*)&bias[tn];
            x.x += bv.x; x.y += bv.y; x.z += bv.z; x.w += bv.w;
            if (RES) {
                const float4 rv = *(const float4*)&resid[(size_t)m * 64 + tn];
                x.x += rv.x; x.y += rv.y; x.z += rv.z; x.w += rv.w;
            }
            *(float4*)&O[(size_t)m * 64 + tn] = x;
        }
    }
}

// ---------------- zero var_llrs ----------------
__global__ void k_zero(float* __restrict__ p, int n) {
    int i = blockIdx.x * blockDim.x + threadIdx.x;
    if (i < n) p[i] = 0.f;
}

// ---------------- decode + segment-sum (atomic) ----------------
__global__ void k_decode(const float* __restrict__ feat, const float* __restrict__ proj_w,
                         const float* __restrict__ proj_b, const int* __restrict__ map,
                         float* __restrict__ var_llrs) {
    int r = blockIdx.x * 4 + (threadIdx.x >> 6);
    int lane = threadIdx.x & 63;
    float v = feat[(size_t)r * 64 + lane] * proj_w[lane];
#pragma unroll
    for (int off = 32; off > 0; off >>= 1) v += __shfl_down(v, off);
    if (lane == 0) {
        int m = r >> 2, b = r & 3;
        atomicAdd(&var_llrs[b * CV + map[m]], v + proj_b[0]);
    }
}

// ---------------- final sigmoid ----------------
__global__ void k_final(const float* __restrict__ var_llrs, const float* __restrict__ llr,
                        float* __restrict__ out) {
    int i = blockIdx.x * blockDim.x + threadIdx.x;   // B*V
    float x = var_llrs[i] + llr[i];
    out[i] = 1.f / (1.f + expf(-x));
}

extern "C" void kernel_launch(void* const* d_in, const int* in_sizes, int n_in,
                              void* d_out, int out_size, void* d_ws, size_t ws_size,
                              hipStream_t stream) {
    const float* llr   = (const float*)d_in[0];
    const int*   map   = (const int*)d_in[1];
    const int*   types = (const int*)d_in[2];
    const float* Avc   = (const float*)d_in[3];   // var_to_check_adjacency
    const float* Acv   = (const float*)d_in[4];   // check_to_var_adjacency
    const float* w_in  = (const float*)d_in[5];
    const float* b_in  = (const float*)d_in[6];
    const float* temb  = (const float*)d_in[7];
    const float* w1v   = (const float*)d_in[8];
    const float* b1v   = (const float*)d_in[9];
    const float* w2v   = (const float*)d_in[10];
    const float* b2v   = (const float*)d_in[11];
    const float* w1c   = (const float*)d_in[12];
    const float* b1c   = (const float*)d_in[13];
    const float* w2c   = (const float*)d_in[14];
    const float* b2c   = (const float*)d_in[15];
    const float* projw = (const float*)d_in[16];
    const float* projb = (const float*)d_in[17];
    float* out = (float*)d_out;

    float* feat = (float*)d_ws;                       // RR*64   =  8 MB
    float* in2  = feat + (size_t)RR * 64;             // RR*192  = 24 MB
    float* hid  = in2 + (size_t)RR * 192;             // RR*128  = 16 MB
    float* wcat = hid + (size_t)RR * 128;             // 5*32960
    float* vllr = wcat + (size_t)CL * WCAT_STRIDE;    // 8192

    k_zero<<<(CB * CV + 255) / 256, 256, 0, stream>>>(vllr, CB * CV);
    k_prep<<<(CL * WCAT_STRIDE + 255) / 256, 256, 0, stream>>>(
        w1v, b1v, w2v, b2v, w1c, b1c, w2c, b2c, wcat);
    k_init_feat<<<(RR * CH) / 256, 256, 0, stream>>>(llr, map, w_in, b_in, feat);

    for (int i = 0; i < CL; ++i) {
        float* wc = wcat + (size_t)i * WCAT_STRIDE;
        k_comb<<<(RR * CH) / 256, 256, 0, stream>>>(feat, types, temb + i * CT * CH, in2);
        // v2c / c2v: one 8192x256x8192 GEMM per adjacency, fused over blockIdx.z
        k_gemm<1, 0, 0><<<dim3(4, 128, 2), 256, 0, stream>>>(
            Avc, Acv, CM, in2, 0, in2, nullptr, nullptr, CM);
        // MLP GEMM1: hid = relu(in2 @ W1cat + b1cat)   (32768 x 128, K=192)
        k_gemm<0, 1, 0><<<dim3(2, 512, 1), 256, 0, stream>>>(
            in2, in2, 192, wc, 128, hid, wc + 32768, nullptr, 192);
        // MLP GEMM2: feat = hid @ W2cat + b2cat (+ feat residual for i>0)
        if (i == 0)
            k_gemm<0, 2, 0><<<dim3(1, 512, 1), 256, 0, stream>>>(
                hid, hid, 128, wc + 24576, 64, feat, wc + 32896, feat, 128);
        else
            k_gemm<0, 2, 1><<<dim3(1, 512, 1), 256, 0, stream>>>(
                hid, hid, 128, wc + 24576, 64, feat, wc + 32896, feat, 128);
    }

    k_decode<<<RR / 4, 256, 0, stream>>>(feat, projw, projb, map, vllr);
    k_final<<<(CB * CV) / 256, 256, 0, stream>>>(vllr, llr, out);
}

// Round 2
// 2366.396 us; speedup vs baseline: 2.0632x; 2.0632x over previous
//
#include <hip/hip_runtime.h>
#include <math.h>

static constexpr int CB = 4;
static constexpr int CV = 2048;
static constexpr int CM = 8192;
static constexpr int CH = 64;
static constexpr int CL = 5;
static constexpr int CT = 4;
static constexpr int RR = CM * CB;   // 32768 rows (m*4+b)
static constexpr int WCAT_STRIDE = 192 * 128 + 128 * 64 + 128 + 64;  // 32960

typedef float f32x4 __attribute__((ext_vector_type(4)));
typedef short bf16x8 __attribute__((ext_vector_type(8)));
typedef unsigned int u32;
typedef unsigned short u16;

__device__ inline u16 f2bf(float x) {
    u32 u = __float_as_uint(x);
    u += 0x7FFF + ((u >> 16) & 1);
    return (u16)(u >> 16);
}
__device__ inline float bf2f(u16 b) { return __uint_as_float(((u32)b) << 16); }

// ---------------- init: feat[r*64+h] = llr[b, map[m]] * w_in[h] + b_in[h] ----------------
__global__ void k_init_feat(const float* __restrict__ llr, const int* __restrict__ map,
                            const float* __restrict__ w_in, const float* __restrict__ b_in,
                            float* __restrict__ feat) {
    int idx = blockIdx.x * blockDim.x + threadIdx.x;
    int h = idx & 63;
    int r = idx >> 6;
    int m = r >> 2;
    int b = r & 3;
    float v = llr[b * CV + map[m]];
    feat[idx] = v * w_in[h] + b_in[h];
}

// ---------------- comb (f32) into in2 slot 0 ----------------
__global__ void k_comb(const float* __restrict__ feat, const int* __restrict__ types,
                       const float* __restrict__ te, float* __restrict__ in2) {
    int idx = blockIdx.x * blockDim.x + threadIdx.x;
    int h = idx & 63;
    int r = idx >> 6;
    int m = r >> 2;
    int t = types[m];
    t = t < 0 ? 0 : (t > CT - 1 ? CT - 1 : t);
    in2[(size_t)r * 192 + h] = feat[idx] + te[t * CH + h];
}

// ---------------- transposed + bf16-split comb: combT_X[col=b*64+h][n=m] ----------------
__global__ void k_transpose(const float* __restrict__ feat, const int* __restrict__ types,
                            const float* __restrict__ te,
                            u16* __restrict__ BH, u16* __restrict__ BL) {
    __shared__ float tile[64][65];
    __shared__ float teL[4][64];
    __shared__ int ty[64];
    const int tid = threadIdx.x;     // 256
    const int m0 = blockIdx.x * 64;
    teL[tid >> 6][tid & 63] = te[tid];
    if (tid < 64) {
        int t = types[m0 + tid];
        ty[tid] = t < 0 ? 0 : (t > CT - 1 ? CT - 1 : t);
    }
    __syncthreads();
    for (int b = 0; b < 4; ++b) {
        __syncthreads();
        {
            const int mr = tid >> 2, hc = (tid & 3) * 16;
            const float* fp = feat + ((size_t)(m0 + mr) * 4 + b) * 64 + hc;
            const int t = ty[mr];
#pragma unroll
            for (int j = 0; j < 4; ++j) {
                float4 v = *(const float4*)(fp + j * 4);
                tile[mr][hc + j * 4 + 0] = v.x + teL[t][hc + j * 4 + 0];
                tile[mr][hc + j * 4 + 1] = v.y + teL[t][hc + j * 4 + 1];
                tile[mr][hc + j * 4 + 2] = v.z + teL[t][hc + j * 4 + 2];
                tile[mr][hc + j * 4 + 3] = v.w + teL[t][hc + j * 4 + 3];
            }
        }
        __syncthreads();
        {
            const int h = tid & 63, mg = tid >> 6;
            u32 hw[8], lw[8];
#pragma unroll
            for (int q = 0; q < 8; ++q) {
                float v0 = tile[mg * 16 + 2 * q + 0][h];
                float v1 = tile[mg * 16 + 2 * q + 1][h];
                u16 h0 = f2bf(v0), h1 = f2bf(v1);
                u16 g0 = f2bf(v0 - bf2f(h0)), g1 = f2bf(v1 - bf2f(h1));
                hw[q] = (u32)h0 | ((u32)h1 << 16);
                lw[q] = (u32)g0 | ((u32)g1 << 16);
            }
            size_t obase = (size_t)(b * 64 + h) * CM + m0 + mg * 16;
            *(uint4*)(BH + obase) = make_uint4(hw[0], hw[1], hw[2], hw[3]);
            *(uint4*)(BH + obase + 8) = make_uint4(hw[4], hw[5], hw[6], hw[7]);
            *(uint4*)(BL + obase) = make_uint4(lw[0], lw[1], lw[2], lw[3]);
            *(uint4*)(BL + obase + 8) = make_uint4(lw[4], lw[5], lw[6], lw[7]);
        }
    }
}

// ---------------- MFMA bf16x3 adjacency GEMM ----------------
// out pbuf[by][m][col] = sum_k A[m][k] * comb[k][col], by = adj*2 + ksplit
// BM=128, BN=256 (full), BK=32, 512 threads (8 waves, 2x4), K-chunk 4096.
__global__ __launch_bounds__(512, 2) void k_adjmfma(
    const float* __restrict__ A0, const float* __restrict__ A1,
    const u16* __restrict__ BH, const u16* __restrict__ BL,
    float* __restrict__ pbuf) {
    __shared__ char lA[128 * 128];   // row m: [Ah 32bf16 | Al 32bf16], XOR-swizzled
    __shared__ char lB[256 * 128];   // row col: [Bh | Bl], XOR-swizzled

    const int tid = threadIdx.x;
    const int adj = blockIdx.y >> 1;
    const int ks = blockIdx.y & 1;
    const int m0 = blockIdx.x * 128;
    const float* __restrict__ A = adj ? A1 : A0;
    const int kbase = ks * 4096;

    const int lane = tid & 63;
    const int wid = tid >> 6;
    const int wr = wid >> 2;        // 0..1
    const int wc = wid & 3;         // 0..3
    const int l15 = lane & 15, l4 = lane >> 4;

    const int sa_row = tid >> 2, sa_kq = tid & 3;     // A: 128 rows x 4 chunks of 8 floats
    const int sb_col = tid >> 1, sb_part = tid & 1;   // B: 256 cols x {H,L}

    f32x4 acc[4][4] = {};

    for (int k0 = 0; k0 < 4096; k0 += 32) {
        // ---- stage A: 8 fp32 -> split -> 16B H + 16B L
        {
            const float* ap = A + (size_t)(m0 + sa_row) * CM + kbase + k0 + sa_kq * 8;
            float4 v0 = *(const float4*)ap;
            float4 v1 = *(const float4*)(ap + 4);
            float vv[8] = {v0.x, v0.y, v0.z, v0.w, v1.x, v1.y, v1.z, v1.w};
            u32 hw[4], lw[4];
#pragma unroll
            for (int j = 0; j < 4; ++j) {
                float a0 = vv[2 * j], a1 = vv[2 * j + 1];
                u16 h0 = f2bf(a0), h1 = f2bf(a1);
                u16 g0 = f2bf(a0 - bf2f(h0)), g1 = f2bf(a1 - bf2f(h1));
                hw[j] = (u32)h0 | ((u32)h1 << 16);
                lw[j] = (u32)g0 | ((u32)g1 << 16);
            }
            char* base = lA + sa_row * 128;
            const int swz = (sa_row & 7) << 4;
            *(uint4*)(base + ((sa_kq * 16) ^ swz)) = make_uint4(hw[0], hw[1], hw[2], hw[3]);
            *(uint4*)(base + ((64 + sa_kq * 16) ^ swz)) = make_uint4(lw[0], lw[1], lw[2], lw[3]);
        }
        // ---- stage B: copy 64B of combT_H or _L for one col
        {
            const u16* src = (sb_part ? BL : BH) + (size_t)sb_col * CM + kbase + k0;
            char* base = lB + sb_col * 128;
            const int swz = (sb_col & 7) << 4;
            const int lb = sb_part * 64;
#pragma unroll
            for (int j = 0; j < 4; ++j) {
                uint4 v = *(const uint4*)(src + j * 8);
                *(uint4*)(base + ((lb + j * 16) ^ swz)) = v;
            }
        }
        __syncthreads();

        bf16x8 bh[4], bl[4];
#pragma unroll
        for (int nf = 0; nf < 4; ++nf) {
            const int col = wc * 64 + nf * 16 + l15;
            const char* rb = lB + col * 128;
            const int swz = (col & 7) << 4;
            bh[nf] = *(const bf16x8*)(rb + ((l4 * 16) ^ swz));
            bl[nf] = *(const bf16x8*)(rb + ((64 + l4 * 16) ^ swz));
        }
#pragma unroll
        for (int mf = 0; mf < 4; ++mf) {
            const int row = wr * 64 + mf * 16 + l15;
            const char* ra = lA + row * 128;
            const int swz = (row & 7) << 4;
            bf16x8 ah = *(const bf16x8*)(ra + ((l4 * 16) ^ swz));
            bf16x8 al = *(const bf16x8*)(ra + ((64 + l4 * 16) ^ swz));
#pragma unroll
            for (int nf = 0; nf < 4; ++nf) {
                acc[mf][nf] = __builtin_amdgcn_mfma_f32_16x16x32_bf16(ah, bh[nf], acc[mf][nf], 0, 0, 0);
                acc[mf][nf] = __builtin_amdgcn_mfma_f32_16x16x32_bf16(ah, bl[nf], acc[mf][nf], 0, 0, 0);
                acc[mf][nf] = __builtin_amdgcn_mfma_f32_16x16x32_bf16(al, bh[nf], acc[mf][nf], 0, 0, 0);
            }
        }
        __syncthreads();
    }

    float* pb = pbuf + (size_t)blockIdx.y * ((size_t)CM * 256);
#pragma unroll
    for (int mf = 0; mf < 4; ++mf) {
#pragma unroll
        for (int nf = 0; nf < 4; ++nf) {
            const int col = wc * 64 + nf * 16 + l15;
#pragma unroll
            for (int r = 0; r < 4; ++r) {
                const int m = m0 + wr * 64 + mf * 16 + l4 * 4 + r;
                pb[(size_t)m * 256 + col] = acc[mf][nf][r];
            }
        }
    }
}

// ---------------- reduce K-split partials into in2 v2c/c2v slots ----------------
__global__ void k_reduce(const float* __restrict__ pbuf, float* __restrict__ in2) {
    int idx = blockIdx.x * blockDim.x + threadIdx.x;   // 2 adj * 8192 m * 64 f4
    int adj = idx >> 19;
    int rem = idx & ((1 << 19) - 1);
    int m = rem >> 6;
    int f4 = rem & 63;
    size_t o = (size_t)m * 256 + (size_t)f4 * 4;
    const float* p0 = pbuf + (size_t)(adj * 2) * ((size_t)CM * 256);
    const float* p1 = p0 + (size_t)CM * 256;
    float4 a = *(const float4*)(p0 + o);
    float4 b4 = *(const float4*)(p1 + o);
    a.x += b4.x; a.y += b4.y; a.z += b4.z; a.w += b4.w;
    int col = f4 * 4;
    int bb = col >> 6, h = col & 63;
    *(float4*)&in2[((size_t)m * 4 + bb) * 192 + 64 + adj * 64 + h] = a;
}

// ---------------- build packed MLP weights ----------------
__global__ void k_prep(const float* __restrict__ w1v, const float* __restrict__ b1v,
                       const float* __restrict__ w2v, const float* __restrict__ b2v,
                       const float* __restrict__ w1c, const float* __restrict__ b1c,
                       const float* __restrict__ w2c, const float* __restrict__ b2c,
                       float* __restrict__ wcat) {
    int idx = blockIdx.x * blockDim.x + threadIdx.x;
    int total = CL * WCAT_STRIDE;
    if (idx >= total) return;
    int i = idx / WCAT_STRIDE;
    int e = idx % WCAT_STRIDE;
    float v;
    if (e < 24576) {
        int j = e >> 7, k = e & 127;
        if (j < 64)        v = (k < 64) ? w1v[(i * 128 + j) * 64 + k]
                                        : w1c[(i * 128 + j) * 64 + (k - 64)];
        else if (j < 128)  v = (k < 64) ? w1v[(i * 128 + j) * 64 + k] : 0.f;
        else               v = (k < 64) ? 0.f : w1c[(i * 128 + (j - 64)) * 64 + (k - 64)];
    } else if (e < 32768) {
        int e2 = e - 24576; int k = e2 >> 6, h = e2 & 63;
        v = (k < 64) ? w2v[(i * 64 + k) * 64 + h]
                     : w2c[(i * 64 + (k - 64)) * 64 + h];
    } else if (e < 32896) {
        int k = e - 32768;
        v = (k < 64) ? b1v[i * 64 + k] : b1c[i * 64 + (k - 64)];
    } else {
        int h = e - 32896;
        v = b2v[i * 64 + h] + b2c[i * 64 + h];
    }
    wcat[idx] = v;
}

// ---------------- fp32 tiled GEMM (MLP), 64x64x32, 256 thr ----------------
// OMODE 1: O[m*128+c] = relu(x + bias[c]);  OMODE 2: O[m*64+c] = x + bias[c] (+resid)
template<int OMODE, int RES>
__global__ __launch_bounds__(256) void k_gemm(
    const float* __restrict__ A0, int lda,
    const float* __restrict__ Bm, int ldb,
    float* __restrict__ O, const float* __restrict__ bias,
    const float* __restrict__ resid, int K) {
    __shared__ float As[32][64];
    __shared__ float Bs[32][68];

    const int tid = threadIdx.x;
    const int m0 = blockIdx.y * 64;
    const int c0 = blockIdx.x * 64;
    const int tm = (tid & 15) * 4;
    const int tn = (tid >> 4) * 4;
    const int arow = tid & 63;
    const int akg = (tid >> 6) * 8;
    const int bk = tid >> 4;
    const int bc = (tid & 15) * 4;

    float acc[4][4] = {};

    for (int k0 = 0; k0 < K; k0 += 32) {
        const float* Ap = A0 + (size_t)(m0 + arow) * (size_t)lda + k0 + akg;
        float4 a0 = *(const float4*)Ap;
        float4 a1 = *(const float4*)(Ap + 4);
        float4 b0 = *(const float4*)(Bm + (size_t)(k0 + bk) * (size_t)ldb + c0 + bc);
        float4 b1 = *(const float4*)(Bm + (size_t)(k0 + bk + 16) * (size_t)ldb + c0 + bc);
        As[akg + 0][arow] = a0.x;
        As[akg + 1][arow] = a0.y;
        As[akg + 2][arow] = a0.z;
        As[akg + 3][arow] = a0.w;
        As[akg + 4][arow] = a1.x;
        As[akg + 5][arow] = a1.y;
        As[akg + 6][arow] = a1.z;
        As[akg + 7][arow] = a1.w;
        *(float4*)&Bs[bk][bc] = b0;
        *(float4*)&Bs[bk + 16][bc] = b1;
        __syncthreads();
#pragma unroll
        for (int k = 0; k < 32; ++k) {
            float4 av = *(const float4*)&As[k][tm];
            float4 bv = *(const float4*)&Bs[k][tn];
            float a_[4] = {av.x, av.y, av.z, av.w};
            float b_[4] = {bv.x, bv.y, bv.z, bv.w};
#pragma unroll
            for (int i = 0; i < 4; ++i)
#pragma unroll
                for (int j = 0; j < 4; ++j)
                    acc[i][j] = fmaf(a_[i], b_[j], acc[i][j]);
        }
        __syncthreads();
    }

#pragma unroll
    for (int i = 0; i < 4; ++i) {
        int m = m0 + tm + i;
        float4 x = make_float4(acc[i][0], acc[i][1], acc[i][2], acc[i][3]);
        if (OMODE == 1) {
            const float4 bv = *(const float4*)&bias[c0 + tn];
            x.x = fmaxf(x.x + bv.x, 0.f);
            x.y = fmaxf(x.y + bv.y, 0.f);
            x.z = fmaxf(x.z + bv.z, 0.f);
            x.w = fmaxf(x.w + bv.w, 0.f);
            *(float4*)&O[(size_t)m * 128 + c0 + tn] = x;
        } else {
            const float4 bv = *(const float4*)&bias[tn];
            x.x += bv.x; x.y += bv.y; x.z += bv.z; x.w += bv.w;
            if (RES) {
                const float4 rv = *(const float4*)&resid[(size_t)m * 64 + tn];
                x.x += rv.x; x.y += rv.y; x.z += rv.z; x.w += rv.w;
            }
            *(float4*)&O[(size_t)m * 64 + tn] = x;
        }
    }
}

__global__ void k_zero(float* __restrict__ p, int n) {
    int i = blockIdx.x * blockDim.x + threadIdx.x;
    if (i < n) p[i] = 0.f;
}

__global__ void k_decode(const float* __restrict__ feat, const float* __restrict__ proj_w,
                         const float* __restrict__ proj_b, const int* __restrict__ map,
                         float* __restrict__ var_llrs) {
    int r = blockIdx.x * 4 + (threadIdx.x >> 6);
    int lane = threadIdx.x & 63;
    float v = feat[(size_t)r * 64 + lane] * proj_w[lane];
#pragma unroll
    for (int off = 32; off > 0; off >>= 1) v += __shfl_down(v, off);
    if (lane == 0) {
        int m = r >> 2, b = r & 3;
        atomicAdd(&var_llrs[b * CV + map[m]], v + proj_b[0]);
    }
}

__global__ void k_final(const float* __restrict__ var_llrs, const float* __restrict__ llr,
                        float* __restrict__ out) {
    int i = blockIdx.x * blockDim.x + threadIdx.x;
    float x = var_llrs[i] + llr[i];
    out[i] = 1.f / (1.f + expf(-x));
}

extern "C" void kernel_launch(void* const* d_in, const int* in_sizes, int n_in,
                              void* d_out, int out_size, void* d_ws, size_t ws_size,
                              hipStream_t stream) {
    const float* llr   = (const float*)d_in[0];
    const int*   map   = (const int*)d_in[1];
    const int*   types = (const int*)d_in[2];
    const float* Avc   = (const float*)d_in[3];
    const float* Acv   = (const float*)d_in[4];
    const float* w_in  = (const float*)d_in[5];
    const float* b_in  = (const float*)d_in[6];
    const float* temb  = (const float*)d_in[7];
    const float* w1v   = (const float*)d_in[8];
    const float* b1v   = (const float*)d_in[9];
    const float* w2v   = (const float*)d_in[10];
    const float* b2v   = (const float*)d_in[11];
    const float* w1c   = (const float*)d_in[12];
    const float* b1c   = (const float*)d_in[13];
    const float* w2c   = (const float*)d_in[14];
    const float* b2c   = (const float*)d_in[15];
    const float* projw = (const float*)d_in[16];
    const float* projb = (const float*)d_in[17];
    float* out = (float*)d_out;

    float* feat = (float*)d_ws;                          // 8 MB
    float* in2  = feat + (size_t)RR * 64;                // 24 MB
    float* hid  = in2 + (size_t)RR * 192;                // 16 MB
    float* wcat = hid + (size_t)RR * 128;
    float* vllr = wcat + (size_t)CL * WCAT_STRIDE;
    float* pbuf = vllr + 8192;                           // 4 * 8192*256 f32 = 32 MB
    u16* combTH = (u16*)(pbuf + (size_t)4 * CM * 256);   // 4 MB
    u16* combTL = combTH + (size_t)256 * CM;             // 4 MB

    k_zero<<<(CB * CV + 255) / 256, 256, 0, stream>>>(vllr, CB * CV);
    k_prep<<<(CL * WCAT_STRIDE + 255) / 256, 256, 0, stream>>>(
        w1v, b1v, w2v, b2v, w1c, b1c, w2c, b2c, wcat);
    k_init_feat<<<(RR * CH) / 256, 256, 0, stream>>>(llr, map, w_in, b_in, feat);

    for (int i = 0; i < CL; ++i) {
        float* wc = wcat + (size_t)i * WCAT_STRIDE;
        const float* te = temb + i * CT * CH;
        k_comb<<<(RR * CH) / 256, 256, 0, stream>>>(feat, types, te, in2);
        k_transpose<<<CM / 64, 256, 0, stream>>>(feat, types, te, combTH, combTL);
        k_adjmfma<<<dim3(64, 4), 512, 0, stream>>>(Avc, Acv, combTH, combTL, pbuf);
        k_reduce<<<(2 * CM * 64) / 256, 256, 0, stream>>>(pbuf, in2);
        k_gemm<1, 0><<<dim3(2, 512), 256, 0, stream>>>(
            in2, 192, wc, 128, hid, wc + 32768, nullptr, 192);
        if (i == 0)
            k_gemm<2, 0><<<dim3(1, 512), 256, 0, stream>>>(
                hid, 128, wc + 24576, 64, feat, wc + 32896, feat, 128);
        else
            k_gemm<2, 1><<<dim3(1, 512), 256, 0, stream>>>(
                hid, 128, wc + 24576, 64, feat, wc + 32896, feat, 128);
    }

    k_decode<<<RR / 4, 256, 0, stream>>>(feat, projw, projb, map, vllr);
    k_final<<<(CB * CV) / 256, 256, 0, stream>>>(vllr, llr, out);
}

// Round 3
// 1843.929 us; speedup vs baseline: 2.6478x; 1.2833x over previous
//
#include <hip/hip_runtime.h>
#include <math.h>

static constexpr int CB = 4;
static constexpr int CV = 2048;
static constexpr int CM = 8192;
static constexpr int CH = 64;
static constexpr int CL = 5;
static constexpr int CT = 4;
static constexpr int RR = CM * CB;   // 32768 rows (m*4+b)
static constexpr int WCAT_STRIDE = 192 * 128 + 128 * 64 + 128 + 64;  // 32960

typedef float f32x4 __attribute__((ext_vector_type(4)));
typedef short bf16x8 __attribute__((ext_vector_type(8)));
typedef unsigned int u32;
typedef unsigned short u16;

__device__ inline u16 f2bf(float x) {
    u32 u = __float_as_uint(x);
    u += 0x7FFF + ((u >> 16) & 1);
    return (u16)(u >> 16);
}
__device__ inline float bf2f(u16 b) { return __uint_as_float(((u32)b) << 16); }

#define GLOAD16(gp, lp)                                                         \
    __builtin_amdgcn_global_load_lds(                                           \
        (const __attribute__((address_space(1))) unsigned int*)(gp),            \
        (__attribute__((address_space(3))) unsigned int*)(lp), 16, 0, 0)

// ---------------- init ----------------
__global__ void k_init_feat(const float* __restrict__ llr, const int* __restrict__ map,
                            const float* __restrict__ w_in, const float* __restrict__ b_in,
                            float* __restrict__ feat) {
    int idx = blockIdx.x * blockDim.x + threadIdx.x;
    int h = idx & 63;
    int r = idx >> 6;
    int m = r >> 2;
    int b = r & 3;
    float v = llr[b * CV + map[m]];
    feat[idx] = v * w_in[h] + b_in[h];
}

// ---------------- comb (f32) into in2 slot 0 ----------------
__global__ void k_comb(const float* __restrict__ feat, const int* __restrict__ types,
                       const float* __restrict__ te, float* __restrict__ in2) {
    int idx = blockIdx.x * blockDim.x + threadIdx.x;
    int h = idx & 63;
    int r = idx >> 6;
    int m = r >> 2;
    int t = types[m];
    t = t < 0 ? 0 : (t > CT - 1 ? CT - 1 : t);
    in2[(size_t)r * 192 + h] = feat[idx] + te[t * CH + h];
}

// ---------------- Aprep builder: frag-ordered bf16 H|L split of adjacency ----------------
// record (adj, ki, rf): 1024 u16 = [H: lane*8 (lane 0..63)][L: 512 + lane*8]
// lane l: H/L of A[rf*16 + (l&15)][ki*32 + (l>>4)*8 .. +7]
__global__ void k_splitA(const float* __restrict__ Avc, const float* __restrict__ Acv,
                         u16* __restrict__ Aprep) {
    size_t tid = (size_t)blockIdx.x * 256 + threadIdx.x;
    int lane = (int)(tid & 63);
    int rf = (int)((tid >> 6) & 511);
    int ki = (int)((tid >> 15) & 255);
    int adj = (int)(tid >> 23);
    const float* __restrict__ A = adj ? Acv : Avc;
    int r = rf * 16 + (lane & 15);
    int kc = ki * 32 + (lane >> 4) * 8;
    const float* sp = A + (size_t)r * CM + kc;
    float4 v0 = *(const float4*)sp;
    float4 v1 = *(const float4*)(sp + 4);
    float vv[8] = {v0.x, v0.y, v0.z, v0.w, v1.x, v1.y, v1.z, v1.w};
    u32 hw[4], lw[4];
#pragma unroll
    for (int j = 0; j < 4; ++j) {
        float a0 = vv[2 * j], a1 = vv[2 * j + 1];
        u16 h0 = f2bf(a0), h1 = f2bf(a1);
        u16 g0 = f2bf(a0 - bf2f(h0)), g1 = f2bf(a1 - bf2f(h1));
        hw[j] = (u32)h0 | ((u32)h1 << 16);
        lw[j] = (u32)g0 | ((u32)g1 << 16);
    }
    u16* dp = Aprep + ((((size_t)adj * 256 + ki) * 512) + rf) * 1024 + lane * 8;
    *(uint4*)dp = make_uint4(hw[0], hw[1], hw[2], hw[3]);
    *(uint4*)(dp + 512) = make_uint4(lw[0], lw[1], lw[2], lw[3]);
}

// ---------------- Bprep builder: transposed comb as swizzled LDS image ----------------
// Bprep[ki][c][128B]: byte ((q*16)^((c&7)<<4)) <- H of comb[c][ki*32+q*8..+7],
//                     byte (((4+q)*16)^swz)     <- L. (c = b*64+h, k-dim is m)
__global__ void k_transposeB(const float* __restrict__ feat, const int* __restrict__ types,
                             const float* __restrict__ te, char* __restrict__ BprepC) {
    __shared__ float tile[64][65];
    __shared__ float teL[4][64];
    __shared__ int ty[64];
    const int tid = threadIdx.x;     // 256
    const int m0 = blockIdx.x * 64;
    teL[tid >> 6][tid & 63] = te[tid];
    if (tid < 64) {
        int t = types[m0 + tid];
        ty[tid] = t < 0 ? 0 : (t > CT - 1 ? CT - 1 : t);
    }
    __syncthreads();
    for (int b = 0; b < 4; ++b) {
        __syncthreads();
        {
            const int mr = tid >> 2, hc = (tid & 3) * 16;
            const float* fp = feat + ((size_t)(m0 + mr) * 4 + b) * 64 + hc;
            const int t = ty[mr];
#pragma unroll
            for (int j = 0; j < 4; ++j) {
                float4 v = *(const float4*)(fp + j * 4);
                tile[mr][hc + j * 4 + 0] = v.x + teL[t][hc + j * 4 + 0];
                tile[mr][hc + j * 4 + 1] = v.y + teL[t][hc + j * 4 + 1];
                tile[mr][hc + j * 4 + 2] = v.z + teL[t][hc + j * 4 + 2];
                tile[mr][hc + j * 4 + 3] = v.w + teL[t][hc + j * 4 + 3];
            }
        }
        __syncthreads();
        {
            const int h = tid & 63, mg = tid >> 6;
            u32 hw[8], lw[8];
#pragma unroll
            for (int q = 0; q < 8; ++q) {
                float v0 = tile[mg * 16 + 2 * q + 0][h];
                float v1 = tile[mg * 16 + 2 * q + 1][h];
                u16 h0 = f2bf(v0), h1 = f2bf(v1);
                u16 g0 = f2bf(v0 - bf2f(h0)), g1 = f2bf(v1 - bf2f(h1));
                hw[q] = (u32)h0 | ((u32)h1 << 16);
                lw[q] = (u32)g0 | ((u32)g1 << 16);
            }
            const int c = b * 64 + h;
            const int mstart = m0 + mg * 16;
            const int ki = mstart >> 5;
            const int q0 = (mstart >> 3) & 3;
            const int swzc = (c & 7) << 4;
            char* rowp = BprepC + (size_t)ki * 32768 + c * 128;
            *(uint4*)(rowp + (((q0 + 0) * 16) ^ swzc)) = make_uint4(hw[0], hw[1], hw[2], hw[3]);
            *(uint4*)(rowp + (((q0 + 1) * 16) ^ swzc)) = make_uint4(hw[4], hw[5], hw[6], hw[7]);
            *(uint4*)(rowp + (((4 + q0) * 16) ^ swzc)) = make_uint4(lw[0], lw[1], lw[2], lw[3]);
            *(uint4*)(rowp + (((5 + q0) * 16) ^ swzc)) = make_uint4(lw[4], lw[5], lw[6], lw[7]);
        }
    }
}

// ---------------- FAST MFMA adjacency GEMM: A from global (frag-ordered), B dbuf LDS ----------------
// grid (64, 4): by -> (adj, ks). pbuf[by][m][col] partials, K-chunk 4096.
__global__ __launch_bounds__(512, 2) void k_adjmfma_fast(
    const u16* __restrict__ Aprep, const char* __restrict__ BprepC,
    float* __restrict__ pbuf) {
    __shared__ char lB[65536];   // 2 x 32KB

    // XCD-aware swizzle (256 blocks, bijective)
    int lin = blockIdx.y * 64 + blockIdx.x;
    lin = (lin & 7) * 32 + (lin >> 3);
    const int bx = lin & 63;
    const int by = lin >> 6;
    const int adj = by >> 1;
    const int ks = by & 1;

    const int tid = threadIdx.x;
    const int lane = tid & 63;
    const int wid = tid >> 6;
    const int wr = wid >> 2;        // 0..1
    const int wc = wid & 3;         // 0..3
    const int l15 = lane & 15, l4 = lane >> 4;
    const int m0 = bx * 128;
    const int rfbase = bx * 8 + wr * 4;

    f32x4 acc[4][4] = {};
    bf16x8 aHc[4], aLc[4], aHn[4], aLn[4];

    // ---- prologue: issue A(0) and B(0)
    {
        const int ki = ks * 128;
#pragma unroll
        for (int mf = 0; mf < 4; ++mf) {
            const u16* ap = Aprep + ((((size_t)adj * 256 + ki) * 512) + rfbase + mf) * 1024 + lane * 8;
            aHn[mf] = *(const bf16x8*)ap;
            aLn[mf] = *(const bf16x8*)(ap + 512);
        }
        const char* bsrc = BprepC + (size_t)ki * 32768;
#pragma unroll
        for (int j = 0; j < 4; ++j)
            GLOAD16(bsrc + j * 8192 + tid * 16, lB + j * 8192 + tid * 16);
    }

    for (int t = 0; t < 128; ++t) {
        const int buf = t & 1;
        // 1. move prefetched A(t) into current (compiler inserts vmcnt wait)
#pragma unroll
        for (int mf = 0; mf < 4; ++mf) { aHc[mf] = aHn[mf]; aLc[mf] = aLn[mf]; }
        // 2. issue A(t+1)
        {
            const int ki = ks * 128 + t + 1;   // may run 1 past end -> padded
#pragma unroll
            for (int mf = 0; mf < 4; ++mf) {
                const u16* ap = Aprep + ((((size_t)adj * 256 + ki) * 512) + rfbase + mf) * 1024 + lane * 8;
                aHn[mf] = *(const bf16x8*)ap;
                aLn[mf] = *(const bf16x8*)(ap + 512);
            }
            // 3. stage B(t+1) into other buffer
            const char* bsrc = BprepC + (size_t)ki * 32768;
            char* bdst = lB + (buf ^ 1) * 32768;
#pragma unroll
            for (int j = 0; j < 4; ++j)
                GLOAD16(bsrc + j * 8192 + tid * 16, bdst + j * 8192 + tid * 16);
        }
        // 4. counted wait: 12 newest (8 A-loads + 4 B-lds for t+1) stay in flight
        asm volatile("s_waitcnt vmcnt(12)" ::: "memory");
        // 5. all waves' B(t) staged
        asm volatile("s_barrier" ::: "memory");
        // 6. compute
        {
            const char* lbb = lB + buf * 32768;
            bf16x8 bh[4], bl[4];
#pragma unroll
            for (int nf = 0; nf < 4; ++nf) {
                const int col = wc * 64 + nf * 16 + l15;
                const char* rb = lbb + col * 128;
                const int swz = (col & 7) << 4;
                bh[nf] = *(const bf16x8*)(rb + ((l4 * 16) ^ swz));
                bl[nf] = *(const bf16x8*)(rb + (((4 + l4) * 16) ^ swz));
            }
#pragma unroll
            for (int mf = 0; mf < 4; ++mf) {
#pragma unroll
                for (int nf = 0; nf < 4; ++nf) {
                    acc[mf][nf] = __builtin_amdgcn_mfma_f32_16x16x32_bf16(aHc[mf], bh[nf], acc[mf][nf], 0, 0, 0);
                    acc[mf][nf] = __builtin_amdgcn_mfma_f32_16x16x32_bf16(aHc[mf], bl[nf], acc[mf][nf], 0, 0, 0);
                    acc[mf][nf] = __builtin_amdgcn_mfma_f32_16x16x32_bf16(aLc[mf], bh[nf], acc[mf][nf], 0, 0, 0);
                }
            }
        }
        // 7. reads done before next iteration's stage overwrites
        asm volatile("s_barrier" ::: "memory");
    }

    asm volatile("s_waitcnt vmcnt(0)" ::: "memory");

    float* pb = pbuf + (size_t)by * ((size_t)CM * 256);
#pragma unroll
    for (int mf = 0; mf < 4; ++mf) {
#pragma unroll
        for (int nf = 0; nf < 4; ++nf) {
            const int col = wc * 64 + nf * 16 + l15;
#pragma unroll
            for (int r = 0; r < 4; ++r) {
                const int m = m0 + wr * 64 + mf * 16 + l4 * 4 + r;
                pb[(size_t)m * 256 + col] = acc[mf][nf][r];
            }
        }
    }
}

// ================= FALLBACK (round-2) path =================
__global__ void k_transpose(const float* __restrict__ feat, const int* __restrict__ types,
                            const float* __restrict__ te,
                            u16* __restrict__ BH, u16* __restrict__ BL) {
    __shared__ float tile[64][65];
    __shared__ float teL[4][64];
    __shared__ int ty[64];
    const int tid = threadIdx.x;
    const int m0 = blockIdx.x * 64;
    teL[tid >> 6][tid & 63] = te[tid];
    if (tid < 64) {
        int t = types[m0 + tid];
        ty[tid] = t < 0 ? 0 : (t > CT - 1 ? CT - 1 : t);
    }
    __syncthreads();
    for (int b = 0; b < 4; ++b) {
        __syncthreads();
        {
            const int mr = tid >> 2, hc = (tid & 3) * 16;
            const float* fp = feat + ((size_t)(m0 + mr) * 4 + b) * 64 + hc;
            const int t = ty[mr];
#pragma unroll
            for (int j = 0; j < 4; ++j) {
                float4 v = *(const float4*)(fp + j * 4);
                tile[mr][hc + j * 4 + 0] = v.x + teL[t][hc + j * 4 + 0];
                tile[mr][hc + j * 4 + 1] = v.y + teL[t][hc + j * 4 + 1];
                tile[mr][hc + j * 4 + 2] = v.z + teL[t][hc + j * 4 + 2];
                tile[mr][hc + j * 4 + 3] = v.w + teL[t][hc + j * 4 + 3];
            }
        }
        __syncthreads();
        {
            const int h = tid & 63, mg = tid >> 6;
            u32 hw[8], lw[8];
#pragma unroll
            for (int q = 0; q < 8; ++q) {
                float v0 = tile[mg * 16 + 2 * q + 0][h];
                float v1 = tile[mg * 16 + 2 * q + 1][h];
                u16 h0 = f2bf(v0), h1 = f2bf(v1);
                u16 g0 = f2bf(v0 - bf2f(h0)), g1 = f2bf(v1 - bf2f(h1));
                hw[q] = (u32)h0 | ((u32)h1 << 16);
                lw[q] = (u32)g0 | ((u32)g1 << 16);
            }
            size_t obase = (size_t)(b * 64 + h) * CM + m0 + mg * 16;
            *(uint4*)(BH + obase) = make_uint4(hw[0], hw[1], hw[2], hw[3]);
            *(uint4*)(BH + obase + 8) = make_uint4(hw[4], hw[5], hw[6], hw[7]);
            *(uint4*)(BL + obase) = make_uint4(lw[0], lw[1], lw[2], lw[3]);
            *(uint4*)(BL + obase + 8) = make_uint4(lw[4], lw[5], lw[6], lw[7]);
        }
    }
}

__global__ __launch_bounds__(512, 2) void k_adjmfma_fb(
    const float* __restrict__ A0, const float* __restrict__ A1,
    const u16* __restrict__ BH, const u16* __restrict__ BL,
    float* __restrict__ pbuf) {
    __shared__ char lA[128 * 128];
    __shared__ char lB[256 * 128];

    const int tid = threadIdx.x;
    const int adj = blockIdx.y >> 1;
    const int ks = blockIdx.y & 1;
    const int m0 = blockIdx.x * 128;
    const float* __restrict__ A = adj ? A1 : A0;
    const int kbase = ks * 4096;

    const int lane = tid & 63;
    const int wid = tid >> 6;
    const int wr = wid >> 2;
    const int wc = wid & 3;
    const int l15 = lane & 15, l4 = lane >> 4;

    const int sa_row = tid >> 2, sa_kq = tid & 3;
    const int sb_col = tid >> 1, sb_part = tid & 1;

    f32x4 acc[4][4] = {};

    for (int k0 = 0; k0 < 4096; k0 += 32) {
        {
            const float* ap = A + (size_t)(m0 + sa_row) * CM + kbase + k0 + sa_kq * 8;
            float4 v0 = *(const float4*)ap;
            float4 v1 = *(const float4*)(ap + 4);
            float vv[8] = {v0.x, v0.y, v0.z, v0.w, v1.x, v1.y, v1.z, v1.w};
            u32 hw[4], lw[4];
#pragma unroll
            for (int j = 0; j < 4; ++j) {
                float a0 = vv[2 * j], a1 = vv[2 * j + 1];
                u16 h0 = f2bf(a0), h1 = f2bf(a1);
                u16 g0 = f2bf(a0 - bf2f(h0)), g1 = f2bf(a1 - bf2f(h1));
                hw[j] = (u32)h0 | ((u32)h1 << 16);
                lw[j] = (u32)g0 | ((u32)g1 << 16);
            }
            char* base = lA + sa_row * 128;
            const int swz = (sa_row & 7) << 4;
            *(uint4*)(base + ((sa_kq * 16) ^ swz)) = make_uint4(hw[0], hw[1], hw[2], hw[3]);
            *(uint4*)(base + ((64 + sa_kq * 16) ^ swz)) = make_uint4(lw[0], lw[1], lw[2], lw[3]);
        }
        {
            const u16* src = (sb_part ? BL : BH) + (size_t)sb_col * CM + kbase + k0;
            char* base = lB + sb_col * 128;
            const int swz = (sb_col & 7) << 4;
            const int lb = sb_part * 64;
#pragma unroll
            for (int j = 0; j < 4; ++j) {
                uint4 v = *(const uint4*)(src + j * 8);
                *(uint4*)(base + ((lb + j * 16) ^ swz)) = v;
            }
        }
        __syncthreads();

        bf16x8 bh[4], bl[4];
#pragma unroll
        for (int nf = 0; nf < 4; ++nf) {
            const int col = wc * 64 + nf * 16 + l15;
            const char* rb = lB + col * 128;
            const int swz = (col & 7) << 4;
            bh[nf] = *(const bf16x8*)(rb + ((l4 * 16) ^ swz));
            bl[nf] = *(const bf16x8*)(rb + ((64 + l4 * 16) ^ swz));
        }
#pragma unroll
        for (int mf = 0; mf < 4; ++mf) {
            const int row = wr * 64 + mf * 16 + l15;
            const char* ra = lA + row * 128;
            const int swz = (row & 7) << 4;
            bf16x8 ah = *(const bf16x8*)(ra + ((l4 * 16) ^ swz));
            bf16x8 al = *(const bf16x8*)(ra + ((64 + l4 * 16) ^ swz));
#pragma unroll
            for (int nf = 0; nf < 4; ++nf) {
                acc[mf][nf] = __builtin_amdgcn_mfma_f32_16x16x32_bf16(ah, bh[nf], acc[mf][nf], 0, 0, 0);
                acc[mf][nf] = __builtin_amdgcn_mfma_f32_16x16x32_bf16(ah, bl[nf], acc[mf][nf], 0, 0, 0);
                acc[mf][nf] = __builtin_amdgcn_mfma_f32_16x16x32_bf16(al, bh[nf], acc[mf][nf], 0, 0, 0);
            }
        }
        __syncthreads();
    }

    float* pb = pbuf + (size_t)blockIdx.y * ((size_t)CM * 256);
#pragma unroll
    for (int mf = 0; mf < 4; ++mf) {
#pragma unroll
        for (int nf = 0; nf < 4; ++nf) {
            const int col = wc * 64 + nf * 16 + l15;
#pragma unroll
            for (int r = 0; r < 4; ++r) {
                const int m = m0 + wr * 64 + mf * 16 + l4 * 4 + r;
                pb[(size_t)m * 256 + col] = acc[mf][nf][r];
            }
        }
    }
}

// ---------------- reduce K-split partials into in2 v2c/c2v slots ----------------
__global__ void k_reduce(const float* __restrict__ pbuf, float* __restrict__ in2) {
    int idx = blockIdx.x * blockDim.x + threadIdx.x;
    int adj = idx >> 19;
    int rem = idx & ((1 << 19) - 1);
    int m = rem >> 6;
    int f4 = rem & 63;
    size_t o = (size_t)m * 256 + (size_t)f4 * 4;
    const float* p0 = pbuf + (size_t)(adj * 2) * ((size_t)CM * 256);
    const float* p1 = p0 + (size_t)CM * 256;
    float4 a = *(const float4*)(p0 + o);
    float4 b4 = *(const float4*)(p1 + o);
    a.x += b4.x; a.y += b4.y; a.z += b4.z; a.w += b4.w;
    int col = f4 * 4;
    int bb = col >> 6, h = col & 63;
    *(float4*)&in2[((size_t)m * 4 + bb) * 192 + 64 + adj * 64 + h] = a;
}

// ---------------- packed MLP weights ----------------
__global__ void k_prep(const float* __restrict__ w1v, const float* __restrict__ b1v,
                       const float* __restrict__ w2v, const float* __restrict__ b2v,
                       const float* __restrict__ w1c, const float* __restrict__ b1c,
                       const float* __restrict__ w2c, const float* __restrict__ b2c,
                       float* __restrict__ wcat) {
    int idx = blockIdx.x * blockDim.x + threadIdx.x;
    int total = CL * WCAT_STRIDE;
    if (idx >= total) return;
    int i = idx / WCAT_STRIDE;
    int e = idx % WCAT_STRIDE;
    float v;
    if (e < 24576) {
        int j = e >> 7, k = e & 127;
        if (j < 64)        v = (k < 64) ? w1v[(i * 128 + j) * 64 + k]
                                        : w1c[(i * 128 + j) * 64 + (k - 64)];
        else if (j < 128)  v = (k < 64) ? w1v[(i * 128 + j) * 64 + k] : 0.f;
        else               v = (k < 64) ? 0.f : w1c[(i * 128 + (j - 64)) * 64 + (k - 64)];
    } else if (e < 32768) {
        int e2 = e - 24576; int k = e2 >> 6, h = e2 & 63;
        v = (k < 64) ? w2v[(i * 64 + k) * 64 + h]
                     : w2c[(i * 64 + (k - 64)) * 64 + h];
    } else if (e < 32896) {
        int k = e - 32768;
        v = (k < 64) ? b1v[i * 64 + k] : b1c[i * 64 + (k - 64)];
    } else {
        int h = e - 32896;
        v = b2v[i * 64 + h] + b2c[i * 64 + h];
    }
    wcat[idx] = v;
}

// ---------------- fp32 tiled GEMM (MLP) ----------------
template<int OMODE, int RES>
__global__ __launch_bounds__(256) void k_gemm(
    const float* __restrict__ A0, int lda,
    const float* __restrict__ Bm, int ldb,
    float* __restrict__ O, const float* __restrict__ bias,
    const float* __restrict__ resid, int K) {
    __shared__ float As[32][64];
    __shared__ float Bs[32][68];

    const int tid = threadIdx.x;
    const int m0 = blockIdx.y * 64;
    const int c0 = blockIdx.x * 64;
    const int tm = (tid & 15) * 4;
    const int tn = (tid >> 4) * 4;
    const int arow = tid & 63;
    const int akg = (tid >> 6) * 8;
    const int bk = tid >> 4;
    const int bc = (tid & 15) * 4;

    float acc[4][4] = {};

    for (int k0 = 0; k0 < K; k0 += 32) {
        const float* Ap = A0 + (size_t)(m0 + arow) * (size_t)lda + k0 + akg;
        float4 a0 = *(const float4*)Ap;
        float4 a1 = *(const float4*)(Ap + 4);
        float4 b0 = *(const float4*)(Bm + (size_t)(k0 + bk) * (size_t)ldb + c0 + bc);
        float4 b1 = *(const float4*)(Bm + (size_t)(k0 + bk + 16) * (size_t)ldb + c0 + bc);
        As[akg + 0][arow] = a0.x;
        As[akg + 1][arow] = a0.y;
        As[akg + 2][arow] = a0.z;
        As[akg + 3][arow] = a0.w;
        As[akg + 4][arow] = a1.x;
        As[akg + 5][arow] = a1.y;
        As[akg + 6][arow] = a1.z;
        As[akg + 7][arow] = a1.w;
        *(float4*)&Bs[bk][bc] = b0;
        *(float4*)&Bs[bk + 16][bc] = b1;
        __syncthreads();
#pragma unroll
        for (int k = 0; k < 32; ++k) {
            float4 av = *(const float4*)&As[k][tm];
            float4 bv = *(const float4*)&Bs[k][tn];
            float a_[4] = {av.x, av.y, av.z, av.w};
            float b_[4] = {bv.x, bv.y, bv.z, bv.w};
#pragma unroll
            for (int i = 0; i < 4; ++i)
#pragma unroll
                for (int j = 0; j < 4; ++j)
                    acc[i][j] = fmaf(a_[i], b_[j], acc[i][j]);
        }
        __syncthreads();
    }

#pragma unroll
    for (int i = 0; i < 4; ++i) {
        int m = m0 + tm + i;
        float4 x = make_float4(acc[i][0], acc[i][1], acc[i][2], acc[i][3]);
        if (OMODE == 1) {
            const float4 bv = *(const float4*)&bias[c0 + tn];
            x.x = fmaxf(x.x + bv.x, 0.f);
            x.y = fmaxf(x.y + bv.y, 0.f);
            x.z = fmaxf(x.z + bv.z, 0.f);
            x.w = fmaxf(x.w + bv.w, 0.f);
            *(float4*)&O[(size_t)m * 128 + c0 + tn] = x;
        } else {
            const float4 bv = *(const float4*)&bias[tn];
            x.x += bv.x; x.y += bv.y; x.z += bv.z; x.w += bv.w;
            if (RES) {
                const float4 rv = *(const float4*)&resid[(size_t)m * 64 + tn];
                x.x += rv.x; x.y += rv.y; x.z += rv.z; x.w += rv.w;
            }
            *(float4*)&O[(size_t)m * 64 + tn] = x;
        }
    }
}

__global__ void k_zero(float* __restrict__ p, int n) {
    int i = blockIdx.x * blockDim.x + threadIdx.x;
    if (i < n) p[i] = 0.f;
}

__global__ void k_decode(const float* __restrict__ feat, const float* __restrict__ proj_w,
                         const float* __restrict__ proj_b, const int* __restrict__ map,
                         float* __restrict__ var_llrs) {
    int r = blockIdx.x * 4 + (threadIdx.x >> 6);
    int lane = threadIdx.x & 63;
    float v = feat[(size_t)r * 64 + lane] * proj_w[lane];
#pragma unroll
    for (int off = 32; off > 0; off >>= 1) v += __shfl_down(v, off);
    if (lane == 0) {
        int m = r >> 2, b = r & 3;
        atomicAdd(&var_llrs[b * CV + map[m]], v + proj_b[0]);
    }
}

__global__ void k_final(const float* __restrict__ var_llrs, const float* __restrict__ llr,
                        float* __restrict__ out) {
    int i = blockIdx.x * blockDim.x + threadIdx.x;
    float x = var_llrs[i] + llr[i];
    out[i] = 1.f / (1.f + expf(-x));
}

extern "C" void kernel_launch(void* const* d_in, const int* in_sizes, int n_in,
                              void* d_out, int out_size, void* d_ws, size_t ws_size,
                              hipStream_t stream) {
    const float* llr   = (const float*)d_in[0];
    const int*   map   = (const int*)d_in[1];
    const int*   types = (const int*)d_in[2];
    const float* Avc   = (const float*)d_in[3];
    const float* Acv   = (const float*)d_in[4];
    const float* w_in  = (const float*)d_in[5];
    const float* b_in  = (const float*)d_in[6];
    const float* temb  = (const float*)d_in[7];
    const float* w1v   = (const float*)d_in[8];
    const float* b1v   = (const float*)d_in[9];
    const float* w2v   = (const float*)d_in[10];
    const float* b2v   = (const float*)d_in[11];
    const float* w1c   = (const float*)d_in[12];
    const float* b1c   = (const float*)d_in[13];
    const float* w2c   = (const float*)d_in[14];
    const float* b2c   = (const float*)d_in[15];
    const float* projw = (const float*)d_in[16];
    const float* projb = (const float*)d_in[17];
    float* out = (float*)d_out;

    // ---- workspace layout (bytes) ----
    constexpr size_t OFF_FEAT = 0;
    constexpr size_t OFF_IN2  = OFF_FEAT + (size_t)RR * 64 * 4;       //  8,388,608
    constexpr size_t OFF_HID  = OFF_IN2 + (size_t)RR * 192 * 4;       // 33,554,432
    constexpr size_t OFF_WCAT = OFF_HID + (size_t)RR * 128 * 4;       // 50,331,648
    constexpr size_t OFF_VLLR = OFF_WCAT + (size_t)CL * WCAT_STRIDE * 4;
    constexpr size_t OFF_PBUF = OFF_VLLR + 8192 * 4;
    constexpr size_t OFF_X    = OFF_PBUF + (size_t)4 * CM * 256 * 4;  // 84,578,048
    // fast path
    constexpr size_t BPREP_BYTES = (size_t)256 * 256 * 128 + 32768;   // 8 MB + OOB pad
    constexpr size_t OFF_APREP   = OFF_X + BPREP_BYTES;
    constexpr size_t APREP_BYTES = (size_t)2 * 256 * 512 * 1024 * 2 + (1 << 20) + 4096;
    constexpr size_t NEED_FAST   = OFF_APREP + APREP_BYTES;
    // fallback path
    constexpr size_t OFF_CTH = OFF_X;
    constexpr size_t OFF_CTL = OFF_CTH + (size_t)256 * CM * 2;

    char* ws = (char*)d_ws;
    float* feat = (float*)(ws + OFF_FEAT);
    float* in2  = (float*)(ws + OFF_IN2);
    float* hid  = (float*)(ws + OFF_HID);
    float* wcat = (float*)(ws + OFF_WCAT);
    float* vllr = (float*)(ws + OFF_VLLR);
    float* pbuf = (float*)(ws + OFF_PBUF);

    const bool fast = ws_size >= NEED_FAST;

    k_zero<<<(CB * CV + 255) / 256, 256, 0, stream>>>(vllr, CB * CV);
    k_prep<<<(CL * WCAT_STRIDE + 255) / 256, 256, 0, stream>>>(
        w1v, b1v, w2v, b2v, w1c, b1c, w2c, b2c, wcat);
    k_init_feat<<<(RR * CH) / 256, 256, 0, stream>>>(llr, map, w_in, b_in, feat);

    u16* Aprep = (u16*)(ws + OFF_APREP);
    char* Bprep = ws + OFF_X;
    u16* combTH = (u16*)(ws + OFF_CTH);
    u16* combTL = (u16*)(ws + OFF_CTL);

    if (fast)
        k_splitA<<<65536, 256, 0, stream>>>(Avc, Acv, Aprep);

    for (int i = 0; i < CL; ++i) {
        float* wc = wcat + (size_t)i * WCAT_STRIDE;
        const float* te = temb + i * CT * CH;
        k_comb<<<(RR * CH) / 256, 256, 0, stream>>>(feat, types, te, in2);
        if (fast) {
            k_transposeB<<<CM / 64, 256, 0, stream>>>(feat, types, te, Bprep);
            k_adjmfma_fast<<<dim3(64, 4), 512, 0, stream>>>(Aprep, Bprep, pbuf);
        } else {
            k_transpose<<<CM / 64, 256, 0, stream>>>(feat, types, te, combTH, combTL);
            k_adjmfma_fb<<<dim3(64, 4), 512, 0, stream>>>(Avc, Acv, combTH, combTL, pbuf);
        }
        k_reduce<<<(2 * CM * 64) / 256, 256, 0, stream>>>(pbuf, in2);
        k_gemm<1, 0><<<dim3(2, 512), 256, 0, stream>>>(
            in2, 192, wc, 128, hid, wc + 32768, nullptr, 192);
        if (i == 0)
            k_gemm<2, 0><<<dim3(1, 512), 256, 0, stream>>>(
                hid, 128, wc + 24576, 64, feat, wc + 32896, feat, 128);
        else
            k_gemm<2, 1><<<dim3(1, 512), 256, 0, stream>>>(
                hid, 128, wc + 24576, 64, feat, wc + 32896, feat, 128);
    }

    k_decode<<<RR / 4, 256, 0, stream>>>(feat, projw, projb, map, vllr);
    k_final<<<(CB * CV) / 256, 256, 0, stream>>>(vllr, llr, out);
}

// Round 4
// 1363.371 us; speedup vs baseline: 3.5811x; 1.3525x over previous
//
#include <hip/hip_runtime.h>
#include <math.h>

static constexpr int CB = 4;
static constexpr int CV = 2048;
static constexpr int CM = 8192;
static constexpr int CH = 64;
static constexpr int CL = 5;
static constexpr int CT = 4;
static constexpr int RR = CM * CB;   // 32768 rows (m*4+b)
static constexpr int WCAT_STRIDE = 192 * 128 + 128 * 64 + 128 + 64;  // 32960

typedef float f32x4 __attribute__((ext_vector_type(4)));
typedef short bf16x8 __attribute__((ext_vector_type(8)));
typedef unsigned int u32;
typedef unsigned short u16;

__device__ inline u16 f2bf(float x) {
    u32 u = __float_as_uint(x);
    u += 0x7FFF + ((u >> 16) & 1);
    return (u16)(u >> 16);
}
__device__ inline float bf2f(u16 b) { return __uint_as_float(((u32)b) << 16); }

#define GLOAD16(gp, lp)                                                         \
    __builtin_amdgcn_global_load_lds(                                           \
        (const __attribute__((address_space(1))) unsigned int*)(gp),            \
        (__attribute__((address_space(3))) unsigned int*)(lp), 16, 0, 0)

// ---------------- init ----------------
__global__ void k_init_feat(const float* __restrict__ llr, const int* __restrict__ map,
                            const float* __restrict__ w_in, const float* __restrict__ b_in,
                            float* __restrict__ feat) {
    int idx = blockIdx.x * blockDim.x + threadIdx.x;
    int h = idx & 63;
    int r = idx >> 6;
    int m = r >> 2;
    int b = r & 3;
    float v = llr[b * CV + map[m]];
    feat[idx] = v * w_in[h] + b_in[h];
}

// ---------------- comb (fallback only) ----------------
__global__ void k_comb(const float* __restrict__ feat, const int* __restrict__ types,
                       const float* __restrict__ te, float* __restrict__ in2) {
    int idx = blockIdx.x * blockDim.x + threadIdx.x;
    int h = idx & 63;
    int r = idx >> 6;
    int m = r >> 2;
    int t = types[m];
    t = t < 0 ? 0 : (t > CT - 1 ? CT - 1 : t);
    in2[(size_t)r * 192 + h] = feat[idx] + te[t * CH + h];
}

// ---------------- Aprep builder: frag-ordered bf16 H|L split, 4x ILP ----------------
// record (adj, ki, rf): 1024 u16 = [H: lane*8][L: 512 + lane*8]
// lane l holds A[rf*16 + (l&15)][ki*32 + (l>>4)*8 .. +7]
__global__ void k_splitA(const float* __restrict__ Avc, const float* __restrict__ Acv,
                         u16* __restrict__ Aprep) {
    size_t t = (size_t)blockIdx.x * 256 + threadIdx.x;   // 2^22 threads
    int lane = (int)(t & 63);
    int rf = (int)((t >> 6) & 511);
    int ki4 = (int)((t >> 15) & 63);
    int adj = (int)(t >> 21);
    const float* __restrict__ A = adj ? Acv : Avc;
    int r = rf * 16 + (lane & 15);
    const float* rp = A + (size_t)r * CM + ki4 * 128 + (lane >> 4) * 8;
    float4 v0[4], v1[4];
#pragma unroll
    for (int u = 0; u < 4; ++u) {
        v0[u] = *(const float4*)(rp + u * 32);
        v1[u] = *(const float4*)(rp + u * 32 + 4);
    }
#pragma unroll
    for (int u = 0; u < 4; ++u) {
        float vv[8] = {v0[u].x, v0[u].y, v0[u].z, v0[u].w,
                       v1[u].x, v1[u].y, v1[u].z, v1[u].w};
        u32 hw[4], lw[4];
#pragma unroll
        for (int j = 0; j < 4; ++j) {
            float a0 = vv[2 * j], a1 = vv[2 * j + 1];
            u16 h0 = f2bf(a0), h1 = f2bf(a1);
            u16 g0 = f2bf(a0 - bf2f(h0)), g1 = f2bf(a1 - bf2f(h1));
            hw[j] = (u32)h0 | ((u32)h1 << 16);
            lw[j] = (u32)g0 | ((u32)g1 << 16);
        }
        u16* dp = Aprep + ((((size_t)adj * 256 + ki4 * 4 + u) * 512) + rf) * 1024 + lane * 8;
        *(uint4*)dp = make_uint4(hw[0], hw[1], hw[2], hw[3]);
        *(uint4*)(dp + 512) = make_uint4(lw[0], lw[1], lw[2], lw[3]);
    }
}

// ---------------- Bprep builder (+ comb into in2 slot 0) ----------------
// Bprep[ki][c][128B]: byte ((q*16)^((c&7)<<4)) <- H of comb[c][ki*32+q*8..+7],
//                     byte (((4+q)*16)^swz)     <- L. (c = b*64+h, k-dim is m)
__global__ void k_transposeB(const float* __restrict__ feat, const int* __restrict__ types,
                             const float* __restrict__ te, char* __restrict__ BprepC,
                             float* __restrict__ in2) {
    __shared__ float tile[64][65];
    __shared__ float teL[4][64];
    __shared__ int ty[64];
    const int tid = threadIdx.x;     // 256
    const int m0 = blockIdx.x * 64;
    teL[tid >> 6][tid & 63] = te[tid];
    if (tid < 64) {
        int tt = types[m0 + tid];
        ty[tid] = tt < 0 ? 0 : (tt > CT - 1 ? CT - 1 : tt);
    }
    __syncthreads();
    for (int b = 0; b < 4; ++b) {
        __syncthreads();
        {
            const int mr = tid >> 2, hc = (tid & 3) * 16;
            const float* fp = feat + ((size_t)(m0 + mr) * 4 + b) * 64 + hc;
            float* op = in2 + ((size_t)(m0 + mr) * 4 + b) * 192 + hc;
            const int tt = ty[mr];
#pragma unroll
            for (int j = 0; j < 4; ++j) {
                float4 v = *(const float4*)(fp + j * 4);
                float4 c;
                c.x = v.x + teL[tt][hc + j * 4 + 0];
                c.y = v.y + teL[tt][hc + j * 4 + 1];
                c.z = v.z + teL[tt][hc + j * 4 + 2];
                c.w = v.w + teL[tt][hc + j * 4 + 3];
                tile[mr][hc + j * 4 + 0] = c.x;
                tile[mr][hc + j * 4 + 1] = c.y;
                tile[mr][hc + j * 4 + 2] = c.z;
                tile[mr][hc + j * 4 + 3] = c.w;
                *(float4*)(op + j * 4) = c;
            }
        }
        __syncthreads();
        {
            const int h = tid & 63, mg = tid >> 6;
            u32 hw[8], lw[8];
#pragma unroll
            for (int q = 0; q < 8; ++q) {
                float v0 = tile[mg * 16 + 2 * q + 0][h];
                float v1 = tile[mg * 16 + 2 * q + 1][h];
                u16 h0 = f2bf(v0), h1 = f2bf(v1);
                u16 g0 = f2bf(v0 - bf2f(h0)), g1 = f2bf(v1 - bf2f(h1));
                hw[q] = (u32)h0 | ((u32)h1 << 16);
                lw[q] = (u32)g0 | ((u32)g1 << 16);
            }
            const int c = b * 64 + h;
            const int mstart = m0 + mg * 16;
            const int ki = mstart >> 5;
            const int q0 = (mstart >> 3) & 3;
            const int swzc = (c & 7) << 4;
            char* rowp = BprepC + (size_t)ki * 32768 + c * 128;
            *(uint4*)(rowp + (((q0 + 0) * 16) ^ swzc)) = make_uint4(hw[0], hw[1], hw[2], hw[3]);
            *(uint4*)(rowp + (((q0 + 1) * 16) ^ swzc)) = make_uint4(hw[4], hw[5], hw[6], hw[7]);
            *(uint4*)(rowp + (((4 + q0) * 16) ^ swzc)) = make_uint4(lw[0], lw[1], lw[2], lw[3]);
            *(uint4*)(rowp + (((5 + q0) * 16) ^ swzc)) = make_uint4(lw[4], lw[5], lw[6], lw[7]);
        }
    }
}

// ---------------- FAST MFMA adjacency GEMM: A+B both via global_load_lds frames ----------------
// grid (64, 4): (adj, ks) quarters. Frame = [A 16KB | B 32KB], double-buffered,
// staged 2 steps ahead, counted vmcnt(6), raw barriers (no vmcnt(0) drain).
__global__ __launch_bounds__(512, 1) void k_adjmfma_fast(
    const char* __restrict__ AprepC, const char* __restrict__ BprepC,
    float* __restrict__ pbuf) {
    __shared__ char frames[2][49152];

    // XCD-aware bijective swizzle (256 blocks)
    int lin = blockIdx.y * 64 + blockIdx.x;
    lin = (lin & 7) * 32 + (lin >> 3);
    const int bx = lin & 63;
    const int by = lin >> 6;
    const int adj = by >> 1;
    const int ks = by & 1;

    const int tid = threadIdx.x;
    const int lane = tid & 63;
    const int wid = tid >> 6;
    const int wr = wid >> 2;        // 0..1
    const int wc = wid & 3;         // 0..3
    const int l15 = lane & 15, l4 = lane >> 4;
    const int m0 = bx * 128;

    const size_t abase = (((size_t)adj * 256) * 512 + (size_t)bx * 8) * 2048;

#define STAGE(F, S)                                                              \
    {                                                                            \
        int ki_ = ks * 128 + (S); if (ki_ > 255) ki_ = 255;                      \
        const char* as_ = AprepC + abase + (size_t)ki_ * (512 * 2048);           \
        char* fr_ = &frames[F][0];                                               \
        GLOAD16(as_ + tid * 16, fr_ + tid * 16);                                 \
        GLOAD16(as_ + 8192 + tid * 16, fr_ + 8192 + tid * 16);                   \
        const char* bs_ = BprepC + ((size_t)ki_ << 15);                          \
        GLOAD16(bs_ + tid * 16, fr_ + 16384 + tid * 16);                         \
        GLOAD16(bs_ + 8192 + tid * 16, fr_ + 24576 + tid * 16);                  \
        GLOAD16(bs_ + 16384 + tid * 16, fr_ + 32768 + tid * 16);                 \
        GLOAD16(bs_ + 24576 + tid * 16, fr_ + 40960 + tid * 16);                 \
    }

    f32x4 acc[4][4] = {};

    STAGE(0, 0);
    STAGE(1, 1);

#pragma unroll 2
    for (int s = 0; s < 128; ++s) {
        const int f = s & 1;
        // frame f (step s) loads are the 6 oldest; allow step s+1's 6 in flight
        asm volatile("s_waitcnt vmcnt(6)" ::: "memory");
        asm volatile("s_barrier" ::: "memory");
        const char* fr = &frames[f][0];
        bf16x8 bh[4], bl[4];
#pragma unroll
        for (int nf = 0; nf < 4; ++nf) {
            const int col = wc * 64 + nf * 16 + l15;
            const char* rb = fr + 16384 + col * 128;
            const int swz = (col & 7) << 4;
            bh[nf] = *(const bf16x8*)(rb + ((l4 * 16) ^ swz));
            bl[nf] = *(const bf16x8*)(rb + (((4 + l4) * 16) ^ swz));
        }
#pragma unroll
        for (int mf = 0; mf < 4; ++mf) {
            const char* ra = fr + (wr * 4 + mf) * 2048 + lane * 16;
            bf16x8 ah = *(const bf16x8*)ra;
            bf16x8 al = *(const bf16x8*)(ra + 1024);
#pragma unroll
            for (int nf = 0; nf < 4; ++nf) {
                acc[mf][nf] = __builtin_amdgcn_mfma_f32_16x16x32_bf16(ah, bh[nf], acc[mf][nf], 0, 0, 0);
                acc[mf][nf] = __builtin_amdgcn_mfma_f32_16x16x32_bf16(ah, bl[nf], acc[mf][nf], 0, 0, 0);
                acc[mf][nf] = __builtin_amdgcn_mfma_f32_16x16x32_bf16(al, bh[nf], acc[mf][nf], 0, 0, 0);
            }
        }
        // all waves done reading frame f before re-staging it
        asm volatile("s_barrier" ::: "memory");
        STAGE(f, s + 2);
    }
    asm volatile("s_waitcnt vmcnt(0)" ::: "memory");

    float* pb = pbuf + (size_t)by * ((size_t)CM * 256);
#pragma unroll
    for (int mf = 0; mf < 4; ++mf) {
#pragma unroll
        for (int nf = 0; nf < 4; ++nf) {
            const int col = wc * 64 + nf * 16 + l15;
#pragma unroll
            for (int r = 0; r < 4; ++r) {
                const int m = m0 + wr * 64 + mf * 16 + l4 * 4 + r;
                pb[(size_t)m * 256 + col] = acc[mf][nf][r];
            }
        }
    }
#undef STAGE
}

// ================= FALLBACK (round-2) path =================
__global__ void k_transpose(const float* __restrict__ feat, const int* __restrict__ types,
                            const float* __restrict__ te,
                            u16* __restrict__ BH, u16* __restrict__ BL) {
    __shared__ float tile[64][65];
    __shared__ float teL[4][64];
    __shared__ int ty[64];
    const int tid = threadIdx.x;
    const int m0 = blockIdx.x * 64;
    teL[tid >> 6][tid & 63] = te[tid];
    if (tid < 64) {
        int t = types[m0 + tid];
        ty[tid] = t < 0 ? 0 : (t > CT - 1 ? CT - 1 : t);
    }
    __syncthreads();
    for (int b = 0; b < 4; ++b) {
        __syncthreads();
        {
            const int mr = tid >> 2, hc = (tid & 3) * 16;
            const float* fp = feat + ((size_t)(m0 + mr) * 4 + b) * 64 + hc;
            const int t = ty[mr];
#pragma unroll
            for (int j = 0; j < 4; ++j) {
                float4 v = *(const float4*)(fp + j * 4);
                tile[mr][hc + j * 4 + 0] = v.x + teL[t][hc + j * 4 + 0];
                tile[mr][hc + j * 4 + 1] = v.y + teL[t][hc + j * 4 + 1];
                tile[mr][hc + j * 4 + 2] = v.z + teL[t][hc + j * 4 + 2];
                tile[mr][hc + j * 4 + 3] = v.w + teL[t][hc + j * 4 + 3];
            }
        }
        __syncthreads();
        {
            const int h = tid & 63, mg = tid >> 6;
            u32 hw[8], lw[8];
#pragma unroll
            for (int q = 0; q < 8; ++q) {
                float v0 = tile[mg * 16 + 2 * q + 0][h];
                float v1 = tile[mg * 16 + 2 * q + 1][h];
                u16 h0 = f2bf(v0), h1 = f2bf(v1);
                u16 g0 = f2bf(v0 - bf2f(h0)), g1 = f2bf(v1 - bf2f(h1));
                hw[q] = (u32)h0 | ((u32)h1 << 16);
                lw[q] = (u32)g0 | ((u32)g1 << 16);
            }
            size_t obase = (size_t)(b * 64 + h) * CM + m0 + mg * 16;
            *(uint4*)(BH + obase) = make_uint4(hw[0], hw[1], hw[2], hw[3]);
            *(uint4*)(BH + obase + 8) = make_uint4(hw[4], hw[5], hw[6], hw[7]);
            *(uint4*)(BL + obase) = make_uint4(lw[0], lw[1], lw[2], lw[3]);
            *(uint4*)(BL + obase + 8) = make_uint4(lw[4], lw[5], lw[6], lw[7]);
        }
    }
}

__global__ __launch_bounds__(512, 2) void k_adjmfma_fb(
    const float* __restrict__ A0, const float* __restrict__ A1,
    const u16* __restrict__ BH, const u16* __restrict__ BL,
    float* __restrict__ pbuf) {
    __shared__ char lA[128 * 128];
    __shared__ char lB[256 * 128];

    const int tid = threadIdx.x;
    const int adj = blockIdx.y >> 1;
    const int ks = blockIdx.y & 1;
    const int m0 = blockIdx.x * 128;
    const float* __restrict__ A = adj ? A1 : A0;
    const int kbase = ks * 4096;

    const int lane = tid & 63;
    const int wid = tid >> 6;
    const int wr = wid >> 2;
    const int wc = wid & 3;
    const int l15 = lane & 15, l4 = lane >> 4;

    const int sa_row = tid >> 2, sa_kq = tid & 3;
    const int sb_col = tid >> 1, sb_part = tid & 1;

    f32x4 acc[4][4] = {};

    for (int k0 = 0; k0 < 4096; k0 += 32) {
        {
            const float* ap = A + (size_t)(m0 + sa_row) * CM + kbase + k0 + sa_kq * 8;
            float4 v0 = *(const float4*)ap;
            float4 v1 = *(const float4*)(ap + 4);
            float vv[8] = {v0.x, v0.y, v0.z, v0.w, v1.x, v1.y, v1.z, v1.w};
            u32 hw[4], lw[4];
#pragma unroll
            for (int j = 0; j < 4; ++j) {
                float a0 = vv[2 * j], a1 = vv[2 * j + 1];
                u16 h0 = f2bf(a0), h1 = f2bf(a1);
                u16 g0 = f2bf(a0 - bf2f(h0)), g1 = f2bf(a1 - bf2f(h1));
                hw[j] = (u32)h0 | ((u32)h1 << 16);
                lw[j] = (u32)g0 | ((u32)g1 << 16);
            }
            char* base = lA + sa_row * 128;
            const int swz = (sa_row & 7) << 4;
            *(uint4*)(base + ((sa_kq * 16) ^ swz)) = make_uint4(hw[0], hw[1], hw[2], hw[3]);
            *(uint4*)(base + ((64 + sa_kq * 16) ^ swz)) = make_uint4(lw[0], lw[1], lw[2], lw[3]);
        }
        {
            const u16* src = (sb_part ? BL : BH) + (size_t)sb_col * CM + kbase + k0;
            char* base = lB + sb_col * 128;
            const int swz = (sb_col & 7) << 4;
            const int lb = sb_part * 64;
#pragma unroll
            for (int j = 0; j < 4; ++j) {
                uint4 v = *(const uint4*)(src + j * 8);
                *(uint4*)(base + ((lb + j * 16) ^ swz)) = v;
            }
        }
        __syncthreads();

        bf16x8 bh[4], bl[4];
#pragma unroll
        for (int nf = 0; nf < 4; ++nf) {
            const int col = wc * 64 + nf * 16 + l15;
            const char* rb = lB + col * 128;
            const int swz = (col & 7) << 4;
            bh[nf] = *(const bf16x8*)(rb + ((l4 * 16) ^ swz));
            bl[nf] = *(const bf16x8*)(rb + ((64 + l4 * 16) ^ swz));
        }
#pragma unroll
        for (int mf = 0; mf < 4; ++mf) {
            const int row = wr * 64 + mf * 16 + l15;
            const char* ra = lA + row * 128;
            const int swz = (row & 7) << 4;
            bf16x8 ah = *(const bf16x8*)(ra + ((l4 * 16) ^ swz));
            bf16x8 al = *(const bf16x8*)(ra + ((64 + l4 * 16) ^ swz));
#pragma unroll
            for (int nf = 0; nf < 4; ++nf) {
                acc[mf][nf] = __builtin_amdgcn_mfma_f32_16x16x32_bf16(ah, bh[nf], acc[mf][nf], 0, 0, 0);
                acc[mf][nf] = __builtin_amdgcn_mfma_f32_16x16x32_bf16(ah, bl[nf], acc[mf][nf], 0, 0, 0);
                acc[mf][nf] = __builtin_amdgcn_mfma_f32_16x16x32_bf16(al, bh[nf], acc[mf][nf], 0, 0, 0);
            }
        }
        __syncthreads();
    }

    float* pb = pbuf + (size_t)blockIdx.y * ((size_t)CM * 256);
#pragma unroll
    for (int mf = 0; mf < 4; ++mf) {
#pragma unroll
        for (int nf = 0; nf < 4; ++nf) {
            const int col = wc * 64 + nf * 16 + l15;
#pragma unroll
            for (int r = 0; r < 4; ++r) {
                const int m = m0 + wr * 64 + mf * 16 + l4 * 4 + r;
                pb[(size_t)m * 256 + col] = acc[mf][nf][r];
            }
        }
    }
}

// ---------------- reduce K-split partials into in2 v2c/c2v slots ----------------
__global__ void k_reduce(const float* __restrict__ pbuf, float* __restrict__ in2) {
    int idx = blockIdx.x * blockDim.x + threadIdx.x;
    int adj = idx >> 19;
    int rem = idx & ((1 << 19) - 1);
    int m = rem >> 6;
    int f4 = rem & 63;
    size_t o = (size_t)m * 256 + (size_t)f4 * 4;
    const float* p0 = pbuf + (size_t)(adj * 2) * ((size_t)CM * 256);
    const float* p1 = p0 + (size_t)CM * 256;
    float4 a = *(const float4*)(p0 + o);
    float4 b4 = *(const float4*)(p1 + o);
    a.x += b4.x; a.y += b4.y; a.z += b4.z; a.w += b4.w;
    int col = f4 * 4;
    int bb = col >> 6, h = col & 63;
    *(float4*)&in2[((size_t)m * 4 + bb) * 192 + 64 + adj * 64 + h] = a;
}

// ---------------- packed MLP weights ----------------
__global__ void k_prep(const float* __restrict__ w1v, const float* __restrict__ b1v,
                       const float* __restrict__ w2v, const float* __restrict__ b2v,
                       const float* __restrict__ w1c, const float* __restrict__ b1c,
                       const float* __restrict__ w2c, const float* __restrict__ b2c,
                       float* __restrict__ wcat) {
    int idx = blockIdx.x * blockDim.x + threadIdx.x;
    int total = CL * WCAT_STRIDE;
    if (idx >= total) return;
    int i = idx / WCAT_STRIDE;
    int e = idx % WCAT_STRIDE;
    float v;
    if (e < 24576) {
        int j = e >> 7, k = e & 127;
        if (j < 64)        v = (k < 64) ? w1v[(i * 128 + j) * 64 + k]
                                        : w1c[(i * 128 + j) * 64 + (k - 64)];
        else if (j < 128)  v = (k < 64) ? w1v[(i * 128 + j) * 64 + k] : 0.f;
        else               v = (k < 64) ? 0.f : w1c[(i * 128 + (j - 64)) * 64 + (k - 64)];
    } else if (e < 32768) {
        int e2 = e - 24576; int k = e2 >> 6, h = e2 & 63;
        v = (k < 64) ? w2v[(i * 64 + k) * 64 + h]
                     : w2c[(i * 64 + (k - 64)) * 64 + h];
    } else if (e < 32896) {
        int k = e - 32768;
        v = (k < 64) ? b1v[i * 64 + k] : b1c[i * 64 + (k - 64)];
    } else {
        int h = e - 32896;
        v = b2v[i * 64 + h] + b2c[i * 64 + h];
    }
    wcat[idx] = v;
}

// ---------------- fp32 tiled GEMM (MLP) ----------------
template<int OMODE, int RES>
__global__ __launch_bounds__(256) void k_gemm(
    const float* __restrict__ A0, int lda,
    const float* __restrict__ Bm, int ldb,
    float* __restrict__ O, const float* __restrict__ bias,
    const float* __restrict__ resid, int K) {
    __shared__ float As[32][64];
    __shared__ float Bs[32][68];

    const int tid = threadIdx.x;
    const int m0 = blockIdx.y * 64;
    const int c0 = blockIdx.x * 64;
    const int tm = (tid & 15) * 4;
    const int tn = (tid >> 4) * 4;
    const int arow = tid & 63;
    const int akg = (tid >> 6) * 8;
    const int bk = tid >> 4;
    const int bc = (tid & 15) * 4;

    float acc[4][4] = {};

    for (int k0 = 0; k0 < K; k0 += 32) {
        const float* Ap = A0 + (size_t)(m0 + arow) * (size_t)lda + k0 + akg;
        float4 a0 = *(const float4*)Ap;
        float4 a1 = *(const float4*)(Ap + 4);
        float4 b0 = *(const float4*)(Bm + (size_t)(k0 + bk) * (size_t)ldb + c0 + bc);
        float4 b1 = *(const float4*)(Bm + (size_t)(k0 + bk + 16) * (size_t)ldb + c0 + bc);
        As[akg + 0][arow] = a0.x;
        As[akg + 1][arow] = a0.y;
        As[akg + 2][arow] = a0.z;
        As[akg + 3][arow] = a0.w;
        As[akg + 4][arow] = a1.x;
        As[akg + 5][arow] = a1.y;
        As[akg + 6][arow] = a1.z;
        As[akg + 7][arow] = a1.w;
        *(float4*)&Bs[bk][bc] = b0;
        *(float4*)&Bs[bk + 16][bc] = b1;
        __syncthreads();
#pragma unroll
        for (int k = 0; k < 32; ++k) {
            float4 av = *(const float4*)&As[k][tm];
            float4 bv = *(const float4*)&Bs[k][tn];
            float a_[4] = {av.x, av.y, av.z, av.w};
            float b_[4] = {bv.x, bv.y, bv.z, bv.w};
#pragma unroll
            for (int i = 0; i < 4; ++i)
#pragma unroll
                for (int j = 0; j < 4; ++j)
                    acc[i][j] = fmaf(a_[i], b_[j], acc[i][j]);
        }
        __syncthreads();
    }

#pragma unroll
    for (int i = 0; i < 4; ++i) {
        int m = m0 + tm + i;
        float4 x = make_float4(acc[i][0], acc[i][1], acc[i][2], acc[i][3]);
        if (OMODE == 1) {
            const float4 bv = *(const float4*)&bias[c0 + tn];
            x.x = fmaxf(x.x + bv.x, 0.f);
            x.y = fmaxf(x.y + bv.y, 0.f);
            x.z = fmaxf(x.z + bv.z, 0.f);
            x.w = fmaxf(x.w + bv.w, 0.f);
            *(float4*)&O[(size_t)m * 128 + c0 + tn] = x;
        } else {
            const float4 bv = *(const float4*)&bias[tn];
            x.x += bv.x; x.y += bv.y; x.z += bv.z; x.w += bv.w;
            if (RES) {
                const float4 rv = *(const float4*)&resid[(size_t)m * 64 + tn];
                x.x += rv.x; x.y += rv.y; x.z += rv.z; x.w += rv.w;
            }
            *(float4*)&O[(size_t)m * 64 + tn] = x;
        }
    }
}

__global__ void k_zero(float* __restrict__ p, int n) {
    int i = blockIdx.x * blockDim.x + threadIdx.x;
    if (i < n) p[i] = 0.f;
}

__global__ void k_decode(const float* __restrict__ feat, const float* __restrict__ proj_w,
                         const float* __restrict__ proj_b, const int* __restrict__ map,
                         float* __restrict__ var_llrs) {
    int r = blockIdx.x * 4 + (threadIdx.x >> 6);
    int lane = threadIdx.x & 63;
    float v = feat[(size_t)r * 64 + lane] * proj_w[lane];
#pragma unroll
    for (int off = 32; off > 0; off >>= 1) v += __shfl_down(v, off);
    if (lane == 0) {
        int m = r >> 2, b = r & 3;
        atomicAdd(&var_llrs[b * CV + map[m]], v + proj_b[0]);
    }
}

__global__ void k_final(const float* __restrict__ var_llrs, const float* __restrict__ llr,
                        float* __restrict__ out) {
    int i = blockIdx.x * blockDim.x + threadIdx.x;
    float x = var_llrs[i] + llr[i];
    out[i] = 1.f / (1.f + expf(-x));
}

extern "C" void kernel_launch(void* const* d_in, const int* in_sizes, int n_in,
                              void* d_out, int out_size, void* d_ws, size_t ws_size,
                              hipStream_t stream) {
    const float* llr   = (const float*)d_in[0];
    const int*   map   = (const int*)d_in[1];
    const int*   types = (const int*)d_in[2];
    const float* Avc   = (const float*)d_in[3];
    const float* Acv   = (const float*)d_in[4];
    const float* w_in  = (const float*)d_in[5];
    const float* b_in  = (const float*)d_in[6];
    const float* temb  = (const float*)d_in[7];
    const float* w1v   = (const float*)d_in[8];
    const float* b1v   = (const float*)d_in[9];
    const float* w2v   = (const float*)d_in[10];
    const float* b2v   = (const float*)d_in[11];
    const float* w1c   = (const float*)d_in[12];
    const float* b1c   = (const float*)d_in[13];
    const float* w2c   = (const float*)d_in[14];
    const float* b2c   = (const float*)d_in[15];
    const float* projw = (const float*)d_in[16];
    const float* projb = (const float*)d_in[17];
    float* out = (float*)d_out;

    // ---- workspace layout (bytes) ----
    constexpr size_t OFF_FEAT = 0;
    constexpr size_t OFF_IN2  = OFF_FEAT + (size_t)RR * 64 * 4;
    constexpr size_t OFF_HID  = OFF_IN2 + (size_t)RR * 192 * 4;
    constexpr size_t OFF_WCAT = OFF_HID + (size_t)RR * 128 * 4;
    constexpr size_t OFF_VLLR = OFF_WCAT + (size_t)CL * WCAT_STRIDE * 4;
    constexpr size_t OFF_PBUF = OFF_VLLR + 8192 * 4;
    constexpr size_t OFF_X    = OFF_PBUF + (size_t)4 * CM * 256 * 4;  // 84,578,048
    // fast path
    constexpr size_t BPREP_BYTES = (size_t)256 * 256 * 128 + 32768;
    constexpr size_t OFF_APREP   = OFF_X + BPREP_BYTES;
    constexpr size_t APREP_BYTES = (size_t)2 * 256 * 512 * 2048 + 8192;
    constexpr size_t NEED_FAST   = OFF_APREP + APREP_BYTES;
    // fallback path
    constexpr size_t OFF_CTH = OFF_X;
    constexpr size_t OFF_CTL = OFF_CTH + (size_t)256 * CM * 2;

    char* ws = (char*)d_ws;
    float* feat = (float*)(ws + OFF_FEAT);
    float* in2  = (float*)(ws + OFF_IN2);
    float* hid  = (float*)(ws + OFF_HID);
    float* wcat = (float*)(ws + OFF_WCAT);
    float* vllr = (float*)(ws + OFF_VLLR);
    float* pbuf = (float*)(ws + OFF_PBUF);

    const bool fast = ws_size >= NEED_FAST;

    k_zero<<<(CB * CV + 255) / 256, 256, 0, stream>>>(vllr, CB * CV);
    k_prep<<<(CL * WCAT_STRIDE + 255) / 256, 256, 0, stream>>>(
        w1v, b1v, w2v, b2v, w1c, b1c, w2c, b2c, wcat);
    k_init_feat<<<(RR * CH) / 256, 256, 0, stream>>>(llr, map, w_in, b_in, feat);

    u16* Aprep = (u16*)(ws + OFF_APREP);
    char* Bprep = ws + OFF_X;
    u16* combTH = (u16*)(ws + OFF_CTH);
    u16* combTL = (u16*)(ws + OFF_CTL);

    if (fast)
        k_splitA<<<16384, 256, 0, stream>>>(Avc, Acv, Aprep);

    for (int i = 0; i < CL; ++i) {
        float* wc = wcat + (size_t)i * WCAT_STRIDE;
        const float* te = temb + i * CT * CH;
        if (fast) {
            k_transposeB<<<CM / 64, 256, 0, stream>>>(feat, types, te, Bprep, in2);
            k_adjmfma_fast<<<dim3(64, 4), 512, 0, stream>>>((const char*)Aprep, Bprep, pbuf);
        } else {
            k_comb<<<(RR * CH) / 256, 256, 0, stream>>>(feat, types, te, in2);
            k_transpose<<<CM / 64, 256, 0, stream>>>(feat, types, te, combTH, combTL);
            k_adjmfma_fb<<<dim3(64, 4), 512, 0, stream>>>(Avc, Acv, combTH, combTL, pbuf);
        }
        k_reduce<<<(2 * CM * 64) / 256, 256, 0, stream>>>(pbuf, in2);
        k_gemm<1, 0><<<dim3(2, 512), 256, 0, stream>>>(
            in2, 192, wc, 128, hid, wc + 32768, nullptr, 192);
        if (i == 0)
            k_gemm<2, 0><<<dim3(1, 512), 256, 0, stream>>>(
                hid, 128, wc + 24576, 64, feat, wc + 32896, feat, 128);
        else
            k_gemm<2, 1><<<dim3(1, 512), 256, 0, stream>>>(
                hid, 128, wc + 24576, 64, feat, wc + 32896, feat, 128);
    }

    k_decode<<<RR / 4, 256, 0, stream>>>(feat, projw, projb, map, vllr);
    k_final<<<(CB * CV) / 256, 256, 0, stream>>>(vllr, llr, out);
}

// Round 5
// 1351.572 us; speedup vs baseline: 3.6123x; 1.0087x over previous
//
#include <hip/hip_runtime.h>
#include <math.h>

static constexpr int CB = 4;
static constexpr int CV = 2048;
static constexpr int CM = 8192;
static constexpr int CH = 64;
static constexpr int CL = 5;
static constexpr int CT = 4;
static constexpr int RR = CM * CB;   // 32768 rows (m*4+b)
static constexpr int WCAT_STRIDE = 192 * 128 + 128 * 64 + 128 + 64;  // 32960

typedef float f32x4 __attribute__((ext_vector_type(4)));
typedef short bf16x8 __attribute__((ext_vector_type(8)));
typedef unsigned int u32;
typedef unsigned short u16;

__device__ inline u16 f2bf(float x) {
    u32 u = __float_as_uint(x);
    u += 0x7FFF + ((u >> 16) & 1);
    return (u16)(u >> 16);
}
__device__ inline float bf2f(u16 b) { return __uint_as_float(((u32)b) << 16); }

#define GLOAD16(gp, lp)                                                         \
    __builtin_amdgcn_global_load_lds(                                           \
        (const __attribute__((address_space(1))) unsigned int*)(gp),            \
        (__attribute__((address_space(3))) unsigned int*)(lp), 16, 0, 0)

// ---------------- init ----------------
__global__ void k_init_feat(const float* __restrict__ llr, const int* __restrict__ map,
                            const float* __restrict__ w_in, const float* __restrict__ b_in,
                            float* __restrict__ feat) {
    int idx = blockIdx.x * blockDim.x + threadIdx.x;
    int h = idx & 63;
    int r = idx >> 6;
    int m = r >> 2;
    int b = r & 3;
    float v = llr[b * CV + map[m]];
    feat[idx] = v * w_in[h] + b_in[h];
}

// ---------------- comb (fallback only) ----------------
__global__ void k_comb(const float* __restrict__ feat, const int* __restrict__ types,
                       const float* __restrict__ te, float* __restrict__ in2) {
    int idx = blockIdx.x * blockDim.x + threadIdx.x;
    int h = idx & 63;
    int r = idx >> 6;
    int m = r >> 2;
    int t = types[m];
    t = t < 0 ? 0 : (t > CT - 1 ? CT - 1 : t);
    in2[(size_t)r * 192 + h] = feat[idx] + te[t * CH + h];
}

// ---------------- Aprep builder via LDS transpose: coalesced both sides ----------------
// record (adj, ki, rf) @ byte ((adj*256+ki)*512+rf)*2048:
//   [H 1024B: lane*16][L 1024B: 1024+lane*16]; lane l = A[rf*16+(l&15)][ki*32+(l>>4)*8..+7]
__global__ __launch_bounds__(256) void k_splitA(const float* __restrict__ Avc,
                                                const float* __restrict__ Acv,
                                                u16* __restrict__ Aprep) {
    __shared__ float lds[16][516];
    const int blk = blockIdx.x;          // 16384
    const int adj = blk >> 13;
    const int rem = blk & 8191;
    const int rf = rem & 511;
    const int kig = rem >> 9;            // 0..15 (16 ki each)
    const float* __restrict__ A = adj ? Acv : Avc;
    const int t = threadIdx.x;
    {
        const int rl = t >> 4, cc = t & 15;
        const float* rp = A + (size_t)(rf * 16 + rl) * CM + kig * 512 + cc * 32;
#pragma unroll
        for (int j = 0; j < 8; ++j) {
            float4 v = *(const float4*)(rp + j * 4);
            *(float4*)&lds[rl][cc * 32 + j * 4] = v;
        }
    }
    __syncthreads();
    {
        const int r = t & 15, kl = t >> 4;
        float e[32];
#pragma unroll
        for (int j = 0; j < 8; ++j) {
            float4 v = *(const float4*)&lds[r][kl * 32 + j * 4];
            e[j * 4 + 0] = v.x; e[j * 4 + 1] = v.y;
            e[j * 4 + 2] = v.z; e[j * 4 + 3] = v.w;
        }
        const size_t base = (((size_t)adj * 256 + kig * 16 + kl) * 512 + rf) * 1024;  // u16 units
#pragma unroll
        for (int c = 0; c < 4; ++c) {
            u32 hw[4], lw[4];
#pragma unroll
            for (int j = 0; j < 4; ++j) {
                float a0 = e[c * 8 + 2 * j], a1 = e[c * 8 + 2 * j + 1];
                u16 h0 = f2bf(a0), h1 = f2bf(a1);
                u16 g0 = f2bf(a0 - bf2f(h0)), g1 = f2bf(a1 - bf2f(h1));
                hw[j] = (u32)h0 | ((u32)h1 << 16);
                lw[j] = (u32)g0 | ((u32)g1 << 16);
            }
            u16* dp = Aprep + base + (size_t)(r + 16 * c) * 8;
            *(uint4*)dp = make_uint4(hw[0], hw[1], hw[2], hw[3]);
            *(uint4*)(dp + 512) = make_uint4(lw[0], lw[1], lw[2], lw[3]);
        }
    }
}

// ---------------- Bprep builder (+ compact comb) ----------------
__global__ void k_transposeB(const float* __restrict__ feat, const int* __restrict__ types,
                             const float* __restrict__ te, char* __restrict__ BprepC,
                             float* __restrict__ comb) {
    __shared__ float tile[64][65];
    __shared__ float teL[4][64];
    __shared__ int ty[64];
    const int tid = threadIdx.x;     // 256
    const int m0 = blockIdx.x * 64;
    teL[tid >> 6][tid & 63] = te[tid];
    if (tid < 64) {
        int tt = types[m0 + tid];
        ty[tid] = tt < 0 ? 0 : (tt > CT - 1 ? CT - 1 : tt);
    }
    __syncthreads();
    for (int b = 0; b < 4; ++b) {
        __syncthreads();
        {
            const int mr = tid >> 2, hc = (tid & 3) * 16;
            const float* fp = feat + ((size_t)(m0 + mr) * 4 + b) * 64 + hc;
            float* op = comb + ((size_t)(m0 + mr) * 4 + b) * 64 + hc;
            const int tt = ty[mr];
#pragma unroll
            for (int j = 0; j < 4; ++j) {
                float4 v = *(const float4*)(fp + j * 4);
                float4 c;
                c.x = v.x + teL[tt][hc + j * 4 + 0];
                c.y = v.y + teL[tt][hc + j * 4 + 1];
                c.z = v.z + teL[tt][hc + j * 4 + 2];
                c.w = v.w + teL[tt][hc + j * 4 + 3];
                tile[mr][hc + j * 4 + 0] = c.x;
                tile[mr][hc + j * 4 + 1] = c.y;
                tile[mr][hc + j * 4 + 2] = c.z;
                tile[mr][hc + j * 4 + 3] = c.w;
                *(float4*)(op + j * 4) = c;
            }
        }
        __syncthreads();
        {
            const int h = tid & 63, mg = tid >> 6;
            u32 hw[8], lw[8];
#pragma unroll
            for (int q = 0; q < 8; ++q) {
                float v0 = tile[mg * 16 + 2 * q + 0][h];
                float v1 = tile[mg * 16 + 2 * q + 1][h];
                u16 h0 = f2bf(v0), h1 = f2bf(v1);
                u16 g0 = f2bf(v0 - bf2f(h0)), g1 = f2bf(v1 - bf2f(h1));
                hw[q] = (u32)h0 | ((u32)h1 << 16);
                lw[q] = (u32)g0 | ((u32)g1 << 16);
            }
            const int c = b * 64 + h;
            const int mstart = m0 + mg * 16;
            const int ki = mstart >> 5;
            const int q0 = (mstart >> 3) & 3;
            const int swzc = (c & 7) << 4;
            char* rowp = BprepC + (size_t)ki * 32768 + c * 128;
            *(uint4*)(rowp + (((q0 + 0) * 16) ^ swzc)) = make_uint4(hw[0], hw[1], hw[2], hw[3]);
            *(uint4*)(rowp + (((q0 + 1) * 16) ^ swzc)) = make_uint4(hw[4], hw[5], hw[6], hw[7]);
            *(uint4*)(rowp + (((4 + q0) * 16) ^ swzc)) = make_uint4(lw[0], lw[1], lw[2], lw[3]);
            *(uint4*)(rowp + (((5 + q0) * 16) ^ swzc)) = make_uint4(lw[4], lw[5], lw[6], lw[7]);
        }
    }
}

// ---------------- FAST MFMA adjacency GEMM: 3-deep global_load_lds pipeline ----------------
__global__ __launch_bounds__(512, 1) void k_adjmfma_fast(
    const char* __restrict__ AprepC, const char* __restrict__ BprepC,
    float* __restrict__ pbuf) {
    __shared__ char frames[3][49152];

    // XCD-aware bijective swizzle (256 blocks)
    int lin = blockIdx.y * 64 + blockIdx.x;
    lin = (lin & 7) * 32 + (lin >> 3);
    const int bx = lin & 63;
    const int by = lin >> 6;
    const int adj = by >> 1;
    const int ks = by & 1;

    const int tid = threadIdx.x;
    const int lane = tid & 63;
    const int wid = tid >> 6;
    const int wr = wid >> 2;        // 0..1
    const int wc = wid & 3;         // 0..3
    const int l15 = lane & 15, l4 = lane >> 4;
    const int m0 = bx * 128;

    const size_t abase = (((size_t)adj * 256) * 512 + (size_t)bx * 8) * 2048;

#define STAGE3(FP, S)                                                            \
    {                                                                            \
        int ki_ = ks * 128 + (S); if (ki_ > 255) ki_ = 255;                      \
        const char* as_ = AprepC + abase + (size_t)ki_ * (512 * 2048);           \
        GLOAD16(as_ + tid * 16, (FP) + tid * 16);                                \
        GLOAD16(as_ + 8192 + tid * 16, (FP) + 8192 + tid * 16);                  \
        const char* bs_ = BprepC + ((size_t)ki_ << 15);                          \
        GLOAD16(bs_ + tid * 16, (FP) + 16384 + tid * 16);                        \
        GLOAD16(bs_ + 8192 + tid * 16, (FP) + 24576 + tid * 16);                 \
        GLOAD16(bs_ + 16384 + tid * 16, (FP) + 32768 + tid * 16);                \
        GLOAD16(bs_ + 24576 + tid * 16, (FP) + 40960 + tid * 16);                \
    }

    f32x4 acc[4][4] = {};

    STAGE3(&frames[0][0], 0);
    STAGE3(&frames[1][0], 1);
    STAGE3(&frames[2][0], 2);

    int f = 0;
    for (int s = 0; s < 128; ++s) {
        // frame s's 6 loads are the oldest; frames s+1, s+2 (12 loads) stay in flight
        asm volatile("s_waitcnt vmcnt(12)" ::: "memory");
        asm volatile("s_barrier" ::: "memory");
        const char* fr = &frames[f][0];
        bf16x8 bh[4], bl[4];
#pragma unroll
        for (int nf = 0; nf < 4; ++nf) {
            const int col = wc * 64 + nf * 16 + l15;
            const char* rb = fr + 16384 + col * 128;
            const int swz = (col & 7) << 4;
            bh[nf] = *(const bf16x8*)(rb + ((l4 * 16) ^ swz));
            bl[nf] = *(const bf16x8*)(rb + (((4 + l4) * 16) ^ swz));
        }
#pragma unroll
        for (int mf = 0; mf < 4; ++mf) {
            const char* ra = fr + (wr * 4 + mf) * 2048 + lane * 16;
            bf16x8 ah = *(const bf16x8*)ra;
            bf16x8 al = *(const bf16x8*)(ra + 1024);
#pragma unroll
            for (int nf = 0; nf < 4; ++nf) {
                acc[mf][nf] = __builtin_amdgcn_mfma_f32_16x16x32_bf16(ah, bh[nf], acc[mf][nf], 0, 0, 0);
                acc[mf][nf] = __builtin_amdgcn_mfma_f32_16x16x32_bf16(ah, bl[nf], acc[mf][nf], 0, 0, 0);
                acc[mf][nf] = __builtin_amdgcn_mfma_f32_16x16x32_bf16(al, bh[nf], acc[mf][nf], 0, 0, 0);
            }
        }
        // all waves done reading frame f before re-staging it
        asm volatile("s_barrier" ::: "memory");
        STAGE3(fr, s + 3);
        f = (f == 2) ? 0 : f + 1;
    }
    asm volatile("s_waitcnt vmcnt(0)" ::: "memory");

    float* pb = pbuf + (size_t)by * ((size_t)CM * 256);
#pragma unroll
    for (int mf = 0; mf < 4; ++mf) {
#pragma unroll
        for (int nf = 0; nf < 4; ++nf) {
            const int col = wc * 64 + nf * 16 + l15;
#pragma unroll
            for (int r = 0; r < 4; ++r) {
                const int m = m0 + wr * 64 + mf * 16 + l4 * 4 + r;
                pb[(size_t)m * 256 + col] = acc[mf][nf][r];
            }
        }
    }
#undef STAGE3
}

// ---------------- fused MLP GEMM1: A = [comb | p0+p1 | p2+p3], relu epilogue ----------------
__global__ __launch_bounds__(256) void k_gemm1f(
    const float* __restrict__ comb, const float* __restrict__ pbuf,
    const float* __restrict__ wc, float* __restrict__ hid) {
    __shared__ float As[32][64];
    __shared__ float Bs[32][68];

    const int tid = threadIdx.x;
    const int m0 = blockIdx.y * 64;
    const int c0 = blockIdx.x * 64;
    const int tm = (tid & 15) * 4;
    const int tn = (tid >> 4) * 4;
    const int arow = tid & 63;
    const int akg = (tid >> 6) * 8;
    const int bk = tid >> 4;
    const int bc = (tid & 15) * 4;
    const float* bias = wc + 32768;

    float acc[4][4] = {};

    for (int k0 = 0; k0 < 192; k0 += 32) {
        const int krow = k0 + akg;
        const int r = m0 + arow;
        float4 a0, a1;
        if (krow < 64) {
            const float* ap = comb + (size_t)r * 64 + krow;
            a0 = *(const float4*)ap;
            a1 = *(const float4*)(ap + 4);
        } else {
            const int adj = (krow - 64) >> 6;
            const int h = (krow - 64) & 63;
            const float* p = pbuf + (size_t)(adj * 2) * ((size_t)CM * 256)
                           + (size_t)(r >> 2) * 256 + (r & 3) * 64 + h;
            float4 x0 = *(const float4*)p;
            float4 x1 = *(const float4*)(p + 4);
            float4 y0 = *(const float4*)(p + (size_t)CM * 256);
            float4 y1 = *(const float4*)(p + (size_t)CM * 256 + 4);
            a0.x = x0.x + y0.x; a0.y = x0.y + y0.y; a0.z = x0.z + y0.z; a0.w = x0.w + y0.w;
            a1.x = x1.x + y1.x; a1.y = x1.y + y1.y; a1.z = x1.z + y1.z; a1.w = x1.w + y1.w;
        }
        float4 b0 = *(const float4*)(wc + (size_t)(k0 + bk) * 128 + c0 + bc);
        float4 b1 = *(const float4*)(wc + (size_t)(k0 + bk + 16) * 128 + c0 + bc);
        As[akg + 0][arow] = a0.x;
        As[akg + 1][arow] = a0.y;
        As[akg + 2][arow] = a0.z;
        As[akg + 3][arow] = a0.w;
        As[akg + 4][arow] = a1.x;
        As[akg + 5][arow] = a1.y;
        As[akg + 6][arow] = a1.z;
        As[akg + 7][arow] = a1.w;
        *(float4*)&Bs[bk][bc] = b0;
        *(float4*)&Bs[bk + 16][bc] = b1;
        __syncthreads();
#pragma unroll
        for (int k = 0; k < 32; ++k) {
            float4 av = *(const float4*)&As[k][tm];
            float4 bv = *(const float4*)&Bs[k][tn];
            float a_[4] = {av.x, av.y, av.z, av.w};
            float b_[4] = {bv.x, bv.y, bv.z, bv.w};
#pragma unroll
            for (int i = 0; i < 4; ++i)
#pragma unroll
                for (int j = 0; j < 4; ++j)
                    acc[i][j] = fmaf(a_[i], b_[j], acc[i][j]);
        }
        __syncthreads();
    }

#pragma unroll
    for (int i = 0; i < 4; ++i) {
        int m = m0 + tm + i;
        float4 x = make_float4(acc[i][0], acc[i][1], acc[i][2], acc[i][3]);
        const float4 bv = *(const float4*)&bias[c0 + tn];
        x.x = fmaxf(x.x + bv.x, 0.f);
        x.y = fmaxf(x.y + bv.y, 0.f);
        x.z = fmaxf(x.z + bv.z, 0.f);
        x.w = fmaxf(x.w + bv.w, 0.f);
        *(float4*)&hid[(size_t)m * 128 + c0 + tn] = x;
    }
}

// ================= FALLBACK (round-2) path =================
__global__ void k_transpose(const float* __restrict__ feat, const int* __restrict__ types,
                            const float* __restrict__ te,
                            u16* __restrict__ BH, u16* __restrict__ BL) {
    __shared__ float tile[64][65];
    __shared__ float teL[4][64];
    __shared__ int ty[64];
    const int tid = threadIdx.x;
    const int m0 = blockIdx.x * 64;
    teL[tid >> 6][tid & 63] = te[tid];
    if (tid < 64) {
        int t = types[m0 + tid];
        ty[tid] = t < 0 ? 0 : (t > CT - 1 ? CT - 1 : t);
    }
    __syncthreads();
    for (int b = 0; b < 4; ++b) {
        __syncthreads();
        {
            const int mr = tid >> 2, hc = (tid & 3) * 16;
            const float* fp = feat + ((size_t)(m0 + mr) * 4 + b) * 64 + hc;
            const int t = ty[mr];
#pragma unroll
            for (int j = 0; j < 4; ++j) {
                float4 v = *(const float4*)(fp + j * 4);
                tile[mr][hc + j * 4 + 0] = v.x + teL[t][hc + j * 4 + 0];
                tile[mr][hc + j * 4 + 1] = v.y + teL[t][hc + j * 4 + 1];
                tile[mr][hc + j * 4 + 2] = v.z + teL[t][hc + j * 4 + 2];
                tile[mr][hc + j * 4 + 3] = v.w + teL[t][hc + j * 4 + 3];
            }
        }
        __syncthreads();
        {
            const int h = tid & 63, mg = tid >> 6;
            u32 hw[8], lw[8];
#pragma unroll
            for (int q = 0; q < 8; ++q) {
                float v0 = tile[mg * 16 + 2 * q + 0][h];
                float v1 = tile[mg * 16 + 2 * q + 1][h];
                u16 h0 = f2bf(v0), h1 = f2bf(v1);
                u16 g0 = f2bf(v0 - bf2f(h0)), g1 = f2bf(v1 - bf2f(h1));
                hw[q] = (u32)h0 | ((u32)h1 << 16);
                lw[q] = (u32)g0 | ((u32)g1 << 16);
            }
            size_t obase = (size_t)(b * 64 + h) * CM + m0 + mg * 16;
            *(uint4*)(BH + obase) = make_uint4(hw[0], hw[1], hw[2], hw[3]);
            *(uint4*)(BH + obase + 8) = make_uint4(hw[4], hw[5], hw[6], hw[7]);
            *(uint4*)(BL + obase) = make_uint4(lw[0], lw[1], lw[2], lw[3]);
            *(uint4*)(BL + obase + 8) = make_uint4(lw[4], lw[5], lw[6], lw[7]);
        }
    }
}

__global__ __launch_bounds__(512, 2) void k_adjmfma_fb(
    const float* __restrict__ A0, const float* __restrict__ A1,
    const u16* __restrict__ BH, const u16* __restrict__ BL,
    float* __restrict__ pbuf) {
    __shared__ char lA[128 * 128];
    __shared__ char lB[256 * 128];

    const int tid = threadIdx.x;
    const int adj = blockIdx.y >> 1;
    const int ks = blockIdx.y & 1;
    const int m0 = blockIdx.x * 128;
    const float* __restrict__ A = adj ? A1 : A0;
    const int kbase = ks * 4096;

    const int lane = tid & 63;
    const int wid = tid >> 6;
    const int wr = wid >> 2;
    const int wc = wid & 3;
    const int l15 = lane & 15, l4 = lane >> 4;

    const int sa_row = tid >> 2, sa_kq = tid & 3;
    const int sb_col = tid >> 1, sb_part = tid & 1;

    f32x4 acc[4][4] = {};

    for (int k0 = 0; k0 < 4096; k0 += 32) {
        {
            const float* ap = A + (size_t)(m0 + sa_row) * CM + kbase + k0 + sa_kq * 8;
            float4 v0 = *(const float4*)ap;
            float4 v1 = *(const float4*)(ap + 4);
            float vv[8] = {v0.x, v0.y, v0.z, v0.w, v1.x, v1.y, v1.z, v1.w};
            u32 hw[4], lw[4];
#pragma unroll
            for (int j = 0; j < 4; ++j) {
                float a0 = vv[2 * j], a1 = vv[2 * j + 1];
                u16 h0 = f2bf(a0), h1 = f2bf(a1);
                u16 g0 = f2bf(a0 - bf2f(h0)), g1 = f2bf(a1 - bf2f(h1));
                hw[j] = (u32)h0 | ((u32)h1 << 16);
                lw[j] = (u32)g0 | ((u32)g1 << 16);
            }
            char* base = lA + sa_row * 128;
            const int swz = (sa_row & 7) << 4;
            *(uint4*)(base + ((sa_kq * 16) ^ swz)) = make_uint4(hw[0], hw[1], hw[2], hw[3]);
            *(uint4*)(base + ((64 + sa_kq * 16) ^ swz)) = make_uint4(lw[0], lw[1], lw[2], lw[3]);
        }
        {
            const u16* src = (sb_part ? BL : BH) + (size_t)sb_col * CM + kbase + k0;
            char* base = lB + sb_col * 128;
            const int swz = (sb_col & 7) << 4;
            const int lb = sb_part * 64;
#pragma unroll
            for (int j = 0; j < 4; ++j) {
                uint4 v = *(const uint4*)(src + j * 8);
                *(uint4*)(base + ((lb + j * 16) ^ swz)) = v;
            }
        }
        __syncthreads();

        bf16x8 bh[4], bl[4];
#pragma unroll
        for (int nf = 0; nf < 4; ++nf) {
            const int col = wc * 64 + nf * 16 + l15;
            const char* rb = lB + col * 128;
            const int swz = (col & 7) << 4;
            bh[nf] = *(const bf16x8*)(rb + ((l4 * 16) ^ swz));
            bl[nf] = *(const bf16x8*)(rb + ((64 + l4 * 16) ^ swz));
        }
#pragma unroll
        for (int mf = 0; mf < 4; ++mf) {
            const int row = wr * 64 + mf * 16 + l15;
            const char* ra = lA + row * 128;
            const int swz = (row & 7) << 4;
            bf16x8 ah = *(const bf16x8*)(ra + ((l4 * 16) ^ swz));
            bf16x8 al = *(const bf16x8*)(ra + ((64 + l4 * 16) ^ swz));
#pragma unroll
            for (int nf = 0; nf < 4; ++nf) {
                acc[mf][nf] = __builtin_amdgcn_mfma_f32_16x16x32_bf16(ah, bh[nf], acc[mf][nf], 0, 0, 0);
                acc[mf][nf] = __builtin_amdgcn_mfma_f32_16x16x32_bf16(ah, bl[nf], acc[mf][nf], 0, 0, 0);
                acc[mf][nf] = __builtin_amdgcn_mfma_f32_16x16x32_bf16(al, bh[nf], acc[mf][nf], 0, 0, 0);
            }
        }
        __syncthreads();
    }

    float* pb = pbuf + (size_t)blockIdx.y * ((size_t)CM * 256);
#pragma unroll
    for (int mf = 0; mf < 4; ++mf) {
#pragma unroll
        for (int nf = 0; nf < 4; ++nf) {
            const int col = wc * 64 + nf * 16 + l15;
#pragma unroll
            for (int r = 0; r < 4; ++r) {
                const int m = m0 + wr * 64 + mf * 16 + l4 * 4 + r;
                pb[(size_t)m * 256 + col] = acc[mf][nf][r];
            }
        }
    }
}

__global__ void k_reduce(const float* __restrict__ pbuf, float* __restrict__ in2) {
    int idx = blockIdx.x * blockDim.x + threadIdx.x;
    int adj = idx >> 19;
    int rem = idx & ((1 << 19) - 1);
    int m = rem >> 6;
    int f4 = rem & 63;
    size_t o = (size_t)m * 256 + (size_t)f4 * 4;
    const float* p0 = pbuf + (size_t)(adj * 2) * ((size_t)CM * 256);
    const float* p1 = p0 + (size_t)CM * 256;
    float4 a = *(const float4*)(p0 + o);
    float4 b4 = *(const float4*)(p1 + o);
    a.x += b4.x; a.y += b4.y; a.z += b4.z; a.w += b4.w;
    int col = f4 * 4;
    int bb = col >> 6, h = col & 63;
    *(float4*)&in2[((size_t)m * 4 + bb) * 192 + 64 + adj * 64 + h] = a;
}

// ---------------- packed MLP weights ----------------
__global__ void k_prep(const float* __restrict__ w1v, const float* __restrict__ b1v,
                       const float* __restrict__ w2v, const float* __restrict__ b2v,
                       const float* __restrict__ w1c, const float* __restrict__ b1c,
                       const float* __restrict__ w2c, const float* __restrict__ b2c,
                       float* __restrict__ wcat) {
    int idx = blockIdx.x * blockDim.x + threadIdx.x;
    int total = CL * WCAT_STRIDE;
    if (idx >= total) return;
    int i = idx / WCAT_STRIDE;
    int e = idx % WCAT_STRIDE;
    float v;
    if (e < 24576) {
        int j = e >> 7, k = e & 127;
        if (j < 64)        v = (k < 64) ? w1v[(i * 128 + j) * 64 + k]
                                        : w1c[(i * 128 + j) * 64 + (k - 64)];
        else if (j < 128)  v = (k < 64) ? w1v[(i * 128 + j) * 64 + k] : 0.f;
        else               v = (k < 64) ? 0.f : w1c[(i * 128 + (j - 64)) * 64 + (k - 64)];
    } else if (e < 32768) {
        int e2 = e - 24576; int k = e2 >> 6, h = e2 & 63;
        v = (k < 64) ? w2v[(i * 64 + k) * 64 + h]
                     : w2c[(i * 64 + (k - 64)) * 64 + h];
    } else if (e < 32896) {
        int k = e - 32768;
        v = (k < 64) ? b1v[i * 64 + k] : b1c[i * 64 + (k - 64)];
    } else {
        int h = e - 32896;
        v = b2v[i * 64 + h] + b2c[i * 64 + h];
    }
    wcat[idx] = v;
}

// ---------------- fp32 tiled GEMM (MLP gemm2 + fallback gemm1) ----------------
template<int OMODE, int RES>
__global__ __launch_bounds__(256) void k_gemm(
    const float* __restrict__ A0, int lda,
    const float* __restrict__ Bm, int ldb,
    float* __restrict__ O, const float* __restrict__ bias,
    const float* __restrict__ resid, int K) {
    __shared__ float As[32][64];
    __shared__ float Bs[32][68];

    const int tid = threadIdx.x;
    const int m0 = blockIdx.y * 64;
    const int c0 = blockIdx.x * 64;
    const int tm = (tid & 15) * 4;
    const int tn = (tid >> 4) * 4;
    const int arow = tid & 63;
    const int akg = (tid >> 6) * 8;
    const int bk = tid >> 4;
    const int bc = (tid & 15) * 4;

    float acc[4][4] = {};

    for (int k0 = 0; k0 < K; k0 += 32) {
        const float* Ap = A0 + (size_t)(m0 + arow) * (size_t)lda + k0 + akg;
        float4 a0 = *(const float4*)Ap;
        float4 a1 = *(const float4*)(Ap + 4);
        float4 b0 = *(const float4*)(Bm + (size_t)(k0 + bk) * (size_t)ldb + c0 + bc);
        float4 b1 = *(const float4*)(Bm + (size_t)(k0 + bk + 16) * (size_t)ldb + c0 + bc);
        As[akg + 0][arow] = a0.x;
        As[akg + 1][arow] = a0.y;
        As[akg + 2][arow] = a0.z;
        As[akg + 3][arow] = a0.w;
        As[akg + 4][arow] = a1.x;
        As[akg + 5][arow] = a1.y;
        As[akg + 6][arow] = a1.z;
        As[akg + 7][arow] = a1.w;
        *(float4*)&Bs[bk][bc] = b0;
        *(float4*)&Bs[bk + 16][bc] = b1;
        __syncthreads();
#pragma unroll
        for (int k = 0; k < 32; ++k) {
            float4 av = *(const float4*)&As[k][tm];
            float4 bv = *(const float4*)&Bs[k][tn];
            float a_[4] = {av.x, av.y, av.z, av.w};
            float b_[4] = {bv.x, bv.y, bv.z, bv.w};
#pragma unroll
            for (int i = 0; i < 4; ++i)
#pragma unroll
                for (int j = 0; j < 4; ++j)
                    acc[i][j] = fmaf(a_[i], b_[j], acc[i][j]);
        }
        __syncthreads();
    }

#pragma unroll
    for (int i = 0; i < 4; ++i) {
        int m = m0 + tm + i;
        float4 x = make_float4(acc[i][0], acc[i][1], acc[i][2], acc[i][3]);
        if (OMODE == 1) {
            const float4 bv = *(const float4*)&bias[c0 + tn];
            x.x = fmaxf(x.x + bv.x, 0.f);
            x.y = fmaxf(x.y + bv.y, 0.f);
            x.z = fmaxf(x.z + bv.z, 0.f);
            x.w = fmaxf(x.w + bv.w, 0.f);
            *(float4*)&O[(size_t)m * 128 + c0 + tn] = x;
        } else {
            const float4 bv = *(const float4*)&bias[tn];
            x.x += bv.x; x.y += bv.y; x.z += bv.z; x.w += bv.w;
            if (RES) {
                const float4 rv = *(const float4*)&resid[(size_t)m * 64 + tn];
                x.x += rv.x; x.y += rv.y; x.z += rv.z; x.w += rv.w;
            }
            *(float4*)&O[(size_t)m * 64 + tn] = x;
        }
    }
}

__global__ void k_zero(float* __restrict__ p, int n) {
    int i = blockIdx.x * blockDim.x + threadIdx.x;
    if (i < n) p[i] = 0.f;
}

__global__ void k_decode(const float* __restrict__ feat, const float* __restrict__ proj_w,
                         const float* __restrict__ proj_b, const int* __restrict__ map,
                         float* __restrict__ var_llrs) {
    int r = blockIdx.x * 4 + (threadIdx.x >> 6);
    int lane = threadIdx.x & 63;
    float v = feat[(size_t)r * 64 + lane] * proj_w[lane];
#pragma unroll
    for (int off = 32; off > 0; off >>= 1) v += __shfl_down(v, off);
    if (lane == 0) {
        int m = r >> 2, b = r & 3;
        atomicAdd(&var_llrs[b * CV + map[m]], v + proj_b[0]);
    }
}

__global__ void k_final(const float* __restrict__ var_llrs, const float* __restrict__ llr,
                        float* __restrict__ out) {
    int i = blockIdx.x * blockDim.x + threadIdx.x;
    float x = var_llrs[i] + llr[i];
    out[i] = 1.f / (1.f + expf(-x));
}

extern "C" void kernel_launch(void* const* d_in, const int* in_sizes, int n_in,
                              void* d_out, int out_size, void* d_ws, size_t ws_size,
                              hipStream_t stream) {
    const float* llr   = (const float*)d_in[0];
    const int*   map   = (const int*)d_in[1];
    const int*   types = (const int*)d_in[2];
    const float* Avc   = (const float*)d_in[3];
    const float* Acv   = (const float*)d_in[4];
    const float* w_in  = (const float*)d_in[5];
    const float* b_in  = (const float*)d_in[6];
    const float* temb  = (const float*)d_in[7];
    const float* w1v   = (const float*)d_in[8];
    const float* b1v   = (const float*)d_in[9];
    const float* w2v   = (const float*)d_in[10];
    const float* b2v   = (const float*)d_in[11];
    const float* w1c   = (const float*)d_in[12];
    const float* b1c   = (const float*)d_in[13];
    const float* w2c   = (const float*)d_in[14];
    const float* b2c   = (const float*)d_in[15];
    const float* projw = (const float*)d_in[16];
    const float* projb = (const float*)d_in[17];
    float* out = (float*)d_out;

    // ---- workspace layout (bytes) ----
    constexpr size_t OFF_FEAT = 0;
    constexpr size_t OFF_IN2  = OFF_FEAT + (size_t)RR * 64 * 4;   // fast: comb (8MB of 24MB slot)
    constexpr size_t OFF_HID  = OFF_IN2 + (size_t)RR * 192 * 4;
    constexpr size_t OFF_WCAT = OFF_HID + (size_t)RR * 128 * 4;
    constexpr size_t OFF_VLLR = OFF_WCAT + (size_t)CL * WCAT_STRIDE * 4;
    constexpr size_t OFF_PBUF = OFF_VLLR + 8192 * 4;
    constexpr size_t OFF_X    = OFF_PBUF + (size_t)4 * CM * 256 * 4;  // 84,578,048
    // fast path
    constexpr size_t BPREP_BYTES = (size_t)256 * 256 * 128 + 32768;
    constexpr size_t OFF_APREP   = OFF_X + BPREP_BYTES;
    constexpr size_t APREP_BYTES = (size_t)2 * 256 * 512 * 2048 + 8192;
    constexpr size_t NEED_FAST   = OFF_APREP + APREP_BYTES;
    // fallback path
    constexpr size_t OFF_CTH = OFF_X;
    constexpr size_t OFF_CTL = OFF_CTH + (size_t)256 * CM * 2;

    char* ws = (char*)d_ws;
    float* feat = (float*)(ws + OFF_FEAT);
    float* in2  = (float*)(ws + OFF_IN2);
    float* comb = (float*)(ws + OFF_IN2);
    float* hid  = (float*)(ws + OFF_HID);
    float* wcat = (float*)(ws + OFF_WCAT);
    float* vllr = (float*)(ws + OFF_VLLR);
    float* pbuf = (float*)(ws + OFF_PBUF);

    const bool fast = ws_size >= NEED_FAST;

    k_zero<<<(CB * CV + 255) / 256, 256, 0, stream>>>(vllr, CB * CV);
    k_prep<<<(CL * WCAT_STRIDE + 255) / 256, 256, 0, stream>>>(
        w1v, b1v, w2v, b2v, w1c, b1c, w2c, b2c, wcat);
    k_init_feat<<<(RR * CH) / 256, 256, 0, stream>>>(llr, map, w_in, b_in, feat);

    u16* Aprep = (u16*)(ws + OFF_APREP);
    char* Bprep = ws + OFF_X;
    u16* combTH = (u16*)(ws + OFF_CTH);
    u16* combTL = (u16*)(ws + OFF_CTL);

    if (fast)
        k_splitA<<<16384, 256, 0, stream>>>(Avc, Acv, Aprep);

    for (int i = 0; i < CL; ++i) {
        float* wc = wcat + (size_t)i * WCAT_STRIDE;
        const float* te = temb + i * CT * CH;
        if (fast) {
            k_transposeB<<<CM / 64, 256, 0, stream>>>(feat, types, te, Bprep, comb);
            k_adjmfma_fast<<<dim3(64, 4), 512, 0, stream>>>((const char*)Aprep, Bprep, pbuf);
            k_gemm1f<<<dim3(2, 512), 256, 0, stream>>>(comb, pbuf, wc, hid);
        } else {
            k_comb<<<(RR * CH) / 256, 256, 0, stream>>>(feat, types, te, in2);
            k_transpose<<<CM / 64, 256, 0, stream>>>(feat, types, te, combTH, combTL);
            k_adjmfma_fb<<<dim3(64, 4), 512, 0, stream>>>(Avc, Acv, combTH, combTL, pbuf);
            k_reduce<<<(2 * CM * 64) / 256, 256, 0, stream>>>(pbuf, in2);
            k_gemm<1, 0><<<dim3(2, 512), 256, 0, stream>>>(
                in2, 192, wc, 128, hid, wc + 32768, nullptr, 192);
        }
        if (i == 0)
            k_gemm<2, 0><<<dim3(1, 512), 256, 0, stream>>>(
                hid, 128, wc + 24576, 64, feat, wc + 32896, feat, 128);
        else
            k_gemm<2, 1><<<dim3(1, 512), 256, 0, stream>>>(
                hid, 128, wc + 24576, 64, feat, wc + 32896, feat, 128);
    }

    k_decode<<<RR / 4, 256, 0, stream>>>(feat, projw, projb, map, vllr);
    k_final<<<(CB * CV) / 256, 256, 0, stream>>>(vllr, llr, out);
}